// Round 3
// baseline (3597.259 us; speedup 1.0000x reference)
//
#include <hip/hip_runtime.h>
#include <cmath>

// ---------- helpers: order-preserving float<->uint for atomicMax ----------
// encf never returns 0 for non-NaN inputs, so 0 is the "empty" marker.
__device__ __forceinline__ unsigned encf(float f) {
    unsigned u = __float_as_uint(f);
    return (u & 0x80000000u) ? ~u : (u | 0x80000000u);
}
__device__ __forceinline__ float decf(unsigned v) {
    unsigned u = (v & 0x80000000u) ? (v ^ 0x80000000u) : ~v;
    return __uint_as_float(u);
}

// ---------- K0: encoder. one wave per node. lane = output dim ----------
__global__ __launch_bounds__(64) void k_encoder(
    const float* __restrict__ x,
    const float* __restrict__ Wn, const float* __restrict__ bn,
    const float* __restrict__ Wroot1, const float* __restrict__ b1,
    float* __restrict__ nbuf, float* __restrict__ acc1)
{
    int i = blockIdx.x;
    int j = threadIdx.x;
    __shared__ __align__(16) float nS[64];
    float x0 = x[3*i], x1 = x[3*i+1], x2 = x[3*i+2];
    float nj = fmaxf(fmaf(x2, Wn[128+j], fmaf(x1, Wn[64+j], fmaf(x0, Wn[j], bn[j]))), 0.f);
    size_t o64 = (size_t)i*64 + j;
    nbuf[o64] = nj;
    nS[j] = nj;
    __syncthreads();
    float acc = b1[j];
    const float4* n4 = (const float4*)nS;
    #pragma unroll
    for (int c = 0; c < 16; ++c) {
        float4 f = n4[c];
        acc = fmaf(f.x, Wroot1[(4*c+0)*64+j], acc);
        acc = fmaf(f.y, Wroot1[(4*c+1)*64+j], acc);
        acc = fmaf(f.z, Wroot1[(4*c+2)*64+j], acc);
        acc = fmaf(f.w, Wroot1[(4*c+3)*64+j], acc);
    }
    acc1[o64] = acc;
}

// ---------- K-init: zero Mr, rec=-1, cnt=0 ----------
__global__ void k_init(unsigned* __restrict__ Mr, int4* __restrict__ rec,
                       int* __restrict__ cnt, size_t mrn, int nslots)
{
    size_t gid = (size_t)blockIdx.x*blockDim.x + threadIdx.x;
    size_t stride = (size_t)gridDim.x*blockDim.x;
    uint4* M4 = (uint4*)Mr;
    size_t m4 = mrn >> 2;
    for (size_t k = gid; k < m4; k += stride) M4[k] = make_uint4(0,0,0,0);
    for (size_t k = gid; k < (size_t)nslots; k += stride) rec[k] = make_int4(-1,-1,-1,-1);
    if (gid < 8) cnt[gid] = 0;
}

// ---------- bucket edges by relation ----------
__global__ void k_hist(const int* __restrict__ et, int* __restrict__ cnt, int E)
{
    __shared__ int h[8];
    if (threadIdx.x < 8) h[threadIdx.x] = 0;
    __syncthreads();
    int gid = blockIdx.x*blockDim.x + threadIdx.x;
    int stride = gridDim.x*blockDim.x;
    for (int e = gid; e < E; e += stride) atomicAdd(&h[et[e]], 1);
    __syncthreads();
    if (threadIdx.x < 8) atomicAdd(&cnt[threadIdx.x], h[threadIdx.x]);
}

__global__ void k_scan(const int* __restrict__ cnt, int* __restrict__ cursor, int EPB)
{
    if (threadIdx.x == 0) {
        int o = 0;
        for (int r = 0; r < 8; ++r) {
            cursor[r] = o;
            int c = cnt[r];
            o += ((c + EPB - 1)/EPB)*EPB;   // pad each segment to EPB multiple
        }
    }
}

// scatter packed edge records: (src, dst|rel<<27, a0, a1)
__global__ void k_scatter(const int* __restrict__ ei, const float* __restrict__ ea,
                          const int* __restrict__ et, int* __restrict__ cursor,
                          int4* __restrict__ rec, int E)
{
    __shared__ int h[8];
    __shared__ int base8[8];
    if (threadIdx.x < 8) h[threadIdx.x] = 0;
    __syncthreads();
    int e = blockIdx.x*blockDim.x + threadIdx.x;
    int r = 0, lpos = 0;
    bool act = (e < E);
    if (act) { r = et[e]; lpos = atomicAdd(&h[r], 1); }
    __syncthreads();
    if (threadIdx.x < 8)
        base8[threadIdx.x] = (h[threadIdx.x] > 0) ? atomicAdd(&cursor[threadIdx.x], h[threadIdx.x]) : 0;
    __syncthreads();
    if (act) {
        int4 v = make_int4(ei[e], ei[E + e] | (r << 27),
                           __float_as_int(ea[2*e]), __float_as_int(ea[2*e + 1]));
        rec[base8[r] + lpos] = v;
    }
}

// ---------- K1: layer-1 edge pass. 1 wave/block, 128 edges, single relation.
// lane j holds column j of W1[r] (96 VGPRs). No LDS, no barriers in the hot loop.
__global__ __launch_bounds__(64, 1) void k_edge1(
    const int4* __restrict__ rec, const float* __restrict__ nbuf,
    const float* __restrict__ W1, const float* __restrict__ We,
    const float* __restrict__ be, float* __restrict__ acc1)
{
    int lane = threadIdx.x;
    long base = (long)blockIdx.x * 128;
    int4 h0 = rec[base];
    if (h0.x < 0) return;                    // whole window is padding
    int rel = h0.y >> 27;                    // dst<2^27, rel<8 -> y>=0
    float w[96];
    {
        const float* Wb = W1 + (size_t)rel*96*64 + lane;
        #pragma unroll
        for (int k = 0; k < 96; ++k) w[k] = Wb[k*64];
    }
    float we0 = We[lane & 31], we1 = We[32 + (lane & 31)], bev = be[lane & 31];
    for (int chunk = 0; chunk < 2; ++chunk) {
        int4 my = rec[base + chunk*64 + lane];
        for (int i = 0; i < 64; ++i) {
            int srcv = __shfl(my.x, i);
            if (srcv < 0) break;             // padding is contiguous at tail
            int dstv = __shfl(my.y, i) & 0x07FFFFFF;
            float a0 = __shfl(__int_as_float(my.z), i);
            float a1 = __shfl(__int_as_float(my.w), i);
            // lane l holds e_{l&31} of this edge (upper half duplicates)
            float ev = fmaxf(fmaf(a1, we1, fmaf(a0, we0, bev)), 0.f);
            const float4* n4 = (const float4*)(nbuf + (size_t)srcv*64);
            float acc = 0.f;
            #pragma unroll
            for (int c = 0; c < 16; ++c) {
                float4 f = n4[c];            // all lanes same addr -> broadcast
                acc = fmaf(f.x, w[4*c+0], acc);
                acc = fmaf(f.y, w[4*c+1], acc);
                acc = fmaf(f.z, w[4*c+2], acc);
                acc = fmaf(f.w, w[4*c+3], acc);
            }
            #pragma unroll
            for (int m = 0; m < 32; ++m)
                acc = fmaf(__shfl(ev, m), w[64+m], acc);
            atomicAdd(acc1 + (size_t)dstv*64 + lane, acc);
        }
    }
}

// ---------- K2: fused relu + root2. acc1 -> h (in place); acc2 = h@Wroot2+b2 ----------
__global__ __launch_bounds__(64) void k_hrow(
    float* __restrict__ acc1, float* __restrict__ acc2,
    const float* __restrict__ Wroot2, const float* __restrict__ b2)
{
    int i = blockIdx.x, j = threadIdx.x;
    __shared__ __align__(16) float hS[64];
    size_t o64 = (size_t)i*64 + j;
    float h = fmaxf(acc1[o64], 0.f);
    acc1[o64] = h;
    hS[j] = h;
    __syncthreads();
    float acc = b2[j];
    const float4* h4 = (const float4*)hS;
    #pragma unroll
    for (int c = 0; c < 16; ++c) {
        float4 f = h4[c];
        acc = fmaf(f.x, Wroot2[(4*c+0)*64+j], acc);
        acc = fmaf(f.y, Wroot2[(4*c+1)*64+j], acc);
        acc = fmaf(f.z, Wroot2[(4*c+2)*64+j], acc);
        acc = fmaf(f.w, Wroot2[(4*c+3)*64+j], acc);
    }
    acc2[o64] = acc;
}

// ---------- K3: layer-2 edge pass for ONE relation. atomicMax into Mr ----------
__global__ __launch_bounds__(64, 1) void k_edge2r(
    const int4* __restrict__ rec, const float* __restrict__ hbuf,
    const float* __restrict__ W2, unsigned* __restrict__ Mr, int relWant)
{
    int lane = threadIdx.x;
    long base = (long)blockIdx.x * 128;
    int4 h0 = rec[base];
    if (h0.x < 0) return;
    int rel = h0.y >> 27;
    if (rel != relWant) return;              // not this relation's segment
    float w[64];
    {
        const float* Wb = W2 + (size_t)rel*64*64 + lane;
        #pragma unroll
        for (int k = 0; k < 64; ++k) w[k] = Wb[k*64];
    }
    for (int chunk = 0; chunk < 2; ++chunk) {
        int4 my = rec[base + chunk*64 + lane];
        for (int i = 0; i < 64; ++i) {
            int srcv = __shfl(my.x, i);
            if (srcv < 0) break;
            int dstv = __shfl(my.y, i) & 0x07FFFFFF;
            const float4* h4 = (const float4*)(hbuf + (size_t)srcv*64);
            float acc = 0.f;
            #pragma unroll
            for (int c = 0; c < 16; ++c) {
                float4 f = h4[c];
                acc = fmaf(f.x, w[4*c+0], acc);
                acc = fmaf(f.y, w[4*c+1], acc);
                acc = fmaf(f.z, w[4*c+2], acc);
                acc = fmaf(f.w, w[4*c+3], acc);
            }
            atomicMax(Mr + (size_t)dstv*64 + lane, encf(acc));
        }
    }
}

// ---------- K-merge: acc2 += decode(Mr); re-zero Mr for next relation ----------
__global__ void k_merge(unsigned* __restrict__ Mr, float* __restrict__ acc2,
                        size_t n, int zeroNext)
{
    size_t gid = (size_t)blockIdx.x*blockDim.x + threadIdx.x;
    size_t stride = (size_t)gridDim.x*blockDim.x;
    for (size_t k = gid; k < n; k += stride) {
        unsigned v = Mr[k];
        if (zeroNext) Mr[k] = 0u;
        if (v) acc2[k] += decf(v);           // v==0 <=> no edge of this relation -> +0
    }
}

// ---------- K4: h2 = relu(acc2); o = relu(omega@Wo+bo); head ----------
__global__ __launch_bounds__(64) void k_final(
    const float* __restrict__ acc2, const float* __restrict__ omega,
    const float* __restrict__ Wo, const float* __restrict__ bo,
    const float* __restrict__ Wagg, const float* __restrict__ bagg,
    const float* __restrict__ Wc, const float* __restrict__ bc,
    float* __restrict__ out)
{
    int i = blockIdx.x, j = threadIdx.x;
    __shared__ __align__(16) float cS[128];
    float om0 = omega[2*i], om1 = omega[2*i+1];
    float oj = fmaxf(fmaf(om1, Wo[64+j], fmaf(om0, Wo[j], bo[j])), 0.f);
    float h2 = fmaxf(acc2[(size_t)i*64 + j], 0.f);
    cS[j] = h2;
    cS[64 + j] = oj;
    __syncthreads();
    float t = bagg[j];
    const float4* c4 = (const float4*)cS;
    #pragma unroll
    for (int c = 0; c < 32; ++c) {
        float4 f = c4[c];
        t = fmaf(f.x, Wagg[(4*c+0)*64+j], t);
        t = fmaf(f.y, Wagg[(4*c+1)*64+j], t);
        t = fmaf(f.z, Wagg[(4*c+2)*64+j], t);
        t = fmaf(f.w, Wagg[(4*c+3)*64+j], t);
    }
    t = fmaxf(t, 0.f);
    float part = t * Wc[j];
    #pragma unroll
    for (int off = 32; off; off >>= 1) part += __shfl_xor(part, off);
    if (j == 0) out[i] = tanhf(part + bc[0]) * 5.0f;
}

extern "C" void kernel_launch(void* const* d_in, const int* in_sizes, int n_in,
                              void* d_out, int out_size, void* d_ws, size_t ws_size,
                              hipStream_t stream)
{
    const float* x      = (const float*)d_in[0];
    const int*   ei     = (const int*)d_in[1];
    const float* ea     = (const float*)d_in[2];
    const int*   et     = (const int*)d_in[3];
    const float* omega  = (const float*)d_in[4];
    const float* Wn     = (const float*)d_in[5];
    const float* bn     = (const float*)d_in[6];
    const float* We     = (const float*)d_in[7];
    const float* be     = (const float*)d_in[8];
    const float* Wo     = (const float*)d_in[9];
    const float* bo     = (const float*)d_in[10];
    const float* W1     = (const float*)d_in[11];
    const float* Wroot1 = (const float*)d_in[12];
    const float* b1     = (const float*)d_in[13];
    const float* W2     = (const float*)d_in[14];
    const float* Wroot2 = (const float*)d_in[15];
    const float* b2     = (const float*)d_in[16];
    const float* Wagg   = (const float*)d_in[17];
    const float* bagg   = (const float*)d_in[18];
    const float* Wc     = (const float*)d_in[19];
    const float* bc     = (const float*)d_in[20];
    int N = in_sizes[0] / 3;
    int E = in_sizes[3];
    float* out = (float*)d_out;

    // ---- workspace layout (~103 MB for N=100K, E=1.6M) ----
    float*    nbuf = (float*)d_ws;                      // [N,64] n; reused as acc2
    float*    acc1 = nbuf + (size_t)N*64;               // [N,64] acc1 -> h
    unsigned* Mr   = (unsigned*)(acc1 + (size_t)N*64);  // [N,64] per-relation max buffer
    int nslots = ((E + 127)/128 + 8) * 128;             // padded slot upper bound
    int4* rec   = (int4*)(Mr + (size_t)N*64);           // [nslots] packed edge records
    int* cnt    = (int*)(rec + nslots);                 // [8]
    int* cursor = cnt + 8;                              // [8]
    float* acc2 = nbuf;                                 // alias (n dead after k_edge1)

    int eblocks = nslots / 128;

    k_encoder<<<N, 64, 0, stream>>>(x, Wn, bn, Wroot1, b1, nbuf, acc1);
    k_init<<<1024, 256, 0, stream>>>(Mr, rec, cnt, (size_t)N*64, nslots);
    k_hist<<<1024, 256, 0, stream>>>(et, cnt, E);
    k_scan<<<1, 64, 0, stream>>>(cnt, cursor, 128);
    k_scatter<<<(E + 255)/256, 256, 0, stream>>>(ei, ea, et, cursor, rec, E);
    k_edge1<<<eblocks, 64, 0, stream>>>(rec, nbuf, W1, We, be, acc1);
    k_hrow<<<N, 64, 0, stream>>>(acc1, acc2, Wroot2, b2);
    for (int r = 0; r < 8; ++r) {
        k_edge2r<<<eblocks, 64, 0, stream>>>(rec, acc1, W2, Mr, r);
        k_merge<<<1024, 256, 0, stream>>>(Mr, acc2, (size_t)N*64, (r < 7) ? 1 : 0);
    }
    k_final<<<N, 64, 0, stream>>>(acc2, omega, Wo, bo, Wagg, bagg, Wc, bc, out);
}

// Round 4
// 2779.504 us; speedup vs baseline: 1.2942x; 1.2942x over previous
//
#include <hip/hip_runtime.h>
#include <cmath>

// ---------- helpers: order-preserving float<->uint for atomicMax ----------
// encf never returns 0 for non-NaN inputs, so 0 is the "empty" marker.
__device__ __forceinline__ unsigned encf(float f) {
    unsigned u = __float_as_uint(f);
    return (u & 0x80000000u) ? ~u : (u | 0x80000000u);
}
__device__ __forceinline__ float decf(unsigned v) {
    unsigned u = (v & 0x80000000u) ? (v ^ 0x80000000u) : ~v;
    return __uint_as_float(u);
}

// ---------- K0: encoder. one wave per node. lane = output dim ----------
__global__ __launch_bounds__(64) void k_encoder(
    const float* __restrict__ x,
    const float* __restrict__ Wn, const float* __restrict__ bn,
    const float* __restrict__ Wroot1, const float* __restrict__ b1,
    float* __restrict__ nbuf, float* __restrict__ acc1)
{
    int i = blockIdx.x;
    int j = threadIdx.x;
    __shared__ __align__(16) float nS[64];
    float x0 = x[3*i], x1 = x[3*i+1], x2 = x[3*i+2];
    float nj = fmaxf(fmaf(x2, Wn[128+j], fmaf(x1, Wn[64+j], fmaf(x0, Wn[j], bn[j]))), 0.f);
    size_t o64 = (size_t)i*64 + j;
    nbuf[o64] = nj;
    nS[j] = nj;
    __syncthreads();
    float acc = b1[j];
    const float4* n4 = (const float4*)nS;
    #pragma unroll
    for (int c = 0; c < 16; ++c) {
        float4 f = n4[c];
        acc = fmaf(f.x, Wroot1[(4*c+0)*64+j], acc);
        acc = fmaf(f.y, Wroot1[(4*c+1)*64+j], acc);
        acc = fmaf(f.z, Wroot1[(4*c+2)*64+j], acc);
        acc = fmaf(f.w, Wroot1[(4*c+3)*64+j], acc);
    }
    acc1[o64] = acc;
}

// ---------- K-init: zero Mr planes, rec=-1, cnt=0 ----------
__global__ void k_init(unsigned* __restrict__ Mr, int4* __restrict__ rec,
                       int* __restrict__ cnt, size_t mrn, int nslots)
{
    size_t gid = (size_t)blockIdx.x*blockDim.x + threadIdx.x;
    size_t stride = (size_t)gridDim.x*blockDim.x;
    uint4* M4 = (uint4*)Mr;
    size_t m4 = mrn >> 2;
    for (size_t k = gid; k < m4; k += stride) M4[k] = make_uint4(0,0,0,0);
    for (size_t k = gid; k < (size_t)nslots; k += stride) rec[k] = make_int4(-1,-1,-1,-1);
    if (gid < 8) cnt[gid] = 0;
}

// ---------- bucket edges by relation ----------
__global__ void k_hist(const int* __restrict__ et, int* __restrict__ cnt, int E)
{
    __shared__ int h[8];
    if (threadIdx.x < 8) h[threadIdx.x] = 0;
    __syncthreads();
    int gid = blockIdx.x*blockDim.x + threadIdx.x;
    int stride = gridDim.x*blockDim.x;
    for (int e = gid; e < E; e += stride) atomicAdd(&h[et[e]], 1);
    __syncthreads();
    if (threadIdx.x < 8) atomicAdd(&cnt[threadIdx.x], h[threadIdx.x]);
}

__global__ void k_scan(const int* __restrict__ cnt, int* __restrict__ cursor, int EPB)
{
    if (threadIdx.x == 0) {
        int o = 0;
        for (int r = 0; r < 8; ++r) {
            cursor[r] = o;
            int c = cnt[r];
            o += ((c + EPB - 1)/EPB)*EPB;   // pad each segment to EPB multiple
        }
    }
}

// scatter packed edge records: (src, dst|rel<<27, a0, a1)
__global__ void k_scatter(const int* __restrict__ ei, const float* __restrict__ ea,
                          const int* __restrict__ et, int* __restrict__ cursor,
                          int4* __restrict__ rec, int E)
{
    __shared__ int h[8];
    __shared__ int base8[8];
    if (threadIdx.x < 8) h[threadIdx.x] = 0;
    __syncthreads();
    int e = blockIdx.x*blockDim.x + threadIdx.x;
    int r = 0, lpos = 0;
    bool act = (e < E);
    if (act) { r = et[e]; lpos = atomicAdd(&h[r], 1); }
    __syncthreads();
    if (threadIdx.x < 8)
        base8[threadIdx.x] = (h[threadIdx.x] > 0) ? atomicAdd(&cursor[threadIdx.x], h[threadIdx.x]) : 0;
    __syncthreads();
    if (act) {
        int4 v = make_int4(ei[e], ei[E + e] | (r << 27),
                           __float_as_int(ea[2*e]), __float_as_int(ea[2*e + 1]));
        rec[base8[r] + lpos] = v;
    }
}

// ---------- K1: layer-1 edge pass. 256 threads = 4 waves, each wave owns 128 edges.
// Whole 512-slot window is one relation. lane j holds column j of W1[r].
__global__ __launch_bounds__(256, 4) void k_edge1(
    const int4* __restrict__ rec, const float* __restrict__ nbuf,
    const float* __restrict__ W1, const float* __restrict__ We,
    const float* __restrict__ be, float* __restrict__ acc1)
{
    int lane = threadIdx.x & 63;
    int wave = threadIdx.x >> 6;
    __shared__ __align__(16) float eS[4][64][36];   // per-wave staging; row = 144B (16B-aligned)
    long blk = (long)blockIdx.x * 512;
    int4 h0 = rec[blk];
    if (h0.x < 0) return;                    // whole window is padding
    int rel = h0.y >> 27;
    float w[96];
    {
        const float* Wb = W1 + (size_t)rel*96*64 + lane;
        #pragma unroll
        for (int k = 0; k < 96; ++k) w[k] = Wb[k*64];
    }
    float* myeS = &eS[wave][0][0];
    long wbase = blk + wave*128;
    for (int chunk = 0; chunk < 2; ++chunk) {
        int4 my = rec[wbase + chunk*64 + lane];
        unsigned long long bal = __ballot(my.x >= 0);
        int nval = __popcll(bal);
        if (nval == 0) break;                // padding contiguous at tail
        // each lane stages its OWN edge's 32-dim e-row (same-wave LDS, no barrier needed)
        {
            float a0 = __int_as_float(my.z), a1 = __int_as_float(my.w);
            #pragma unroll
            for (int m = 0; m < 32; ++m)
                myeS[lane*36 + m] = fmaxf(fmaf(a1, We[32+m], fmaf(a0, We[m], be[m])), 0.f);
        }
        for (int i = 0; i < nval; ++i) {
            int srcv = __shfl(my.x, i);
            int dstv = __shfl(my.y, i) & 0x07FFFFFF;
            const float4* n4 = (const float4*)(nbuf + (size_t)srcv*64);
            const float4* e4 = (const float4*)(myeS + i*36);
            float a0 = 0.f, a1 = 0.f, a2 = 0.f, a3 = 0.f;
            #pragma unroll
            for (int c = 0; c < 16; ++c) {
                float4 f = n4[c];            // all lanes same addr -> broadcast
                a0 = fmaf(f.x, w[4*c+0], a0);
                a1 = fmaf(f.y, w[4*c+1], a1);
                a2 = fmaf(f.z, w[4*c+2], a2);
                a3 = fmaf(f.w, w[4*c+3], a3);
            }
            #pragma unroll
            for (int c = 0; c < 8; ++c) {
                float4 f = e4[c];            // LDS broadcast read
                a0 = fmaf(f.x, w[64+4*c+0], a0);
                a1 = fmaf(f.y, w[64+4*c+1], a1);
                a2 = fmaf(f.z, w[64+4*c+2], a2);
                a3 = fmaf(f.w, w[64+4*c+3], a3);
            }
            atomicAdd(acc1 + (size_t)dstv*64 + lane, (a0 + a1) + (a2 + a3));
        }
    }
}

// ---------- K2: fused relu + root2. acc1 -> h (in place); acc2 = h@Wroot2+b2 ----------
__global__ __launch_bounds__(64) void k_hrow(
    float* __restrict__ acc1, float* __restrict__ acc2,
    const float* __restrict__ Wroot2, const float* __restrict__ b2)
{
    int i = blockIdx.x, j = threadIdx.x;
    __shared__ __align__(16) float hS[64];
    size_t o64 = (size_t)i*64 + j;
    float h = fmaxf(acc1[o64], 0.f);
    acc1[o64] = h;
    hS[j] = h;
    __syncthreads();
    float acc = b2[j];
    const float4* h4 = (const float4*)hS;
    #pragma unroll
    for (int c = 0; c < 16; ++c) {
        float4 f = h4[c];
        acc = fmaf(f.x, Wroot2[(4*c+0)*64+j], acc);
        acc = fmaf(f.y, Wroot2[(4*c+1)*64+j], acc);
        acc = fmaf(f.z, Wroot2[(4*c+2)*64+j], acc);
        acc = fmaf(f.w, Wroot2[(4*c+3)*64+j], acc);
    }
    acc2[o64] = acc;
}

// ---------- K3: layer-2 edge pass for relations [g0, g0+Gc). atomicMax into plane (rel-g0) ----------
__global__ __launch_bounds__(256, 4) void k_edge2g(
    const int4* __restrict__ rec, const float* __restrict__ hbuf,
    const float* __restrict__ W2, unsigned* __restrict__ Mr,
    int g0, int Gc, size_t planeElems)
{
    int lane = threadIdx.x & 63;
    int wave = threadIdx.x >> 6;
    long blk = (long)blockIdx.x * 512;
    int4 h0 = rec[blk];
    if (h0.x < 0) return;
    int rel = h0.y >> 27;
    int p = rel - g0;
    if (p < 0 || p >= Gc) return;            // not in this pass's relation group
    unsigned* M = Mr + (size_t)p * planeElems;
    float w[64];
    {
        const float* Wb = W2 + (size_t)rel*64*64 + lane;
        #pragma unroll
        for (int k = 0; k < 64; ++k) w[k] = Wb[k*64];
    }
    long wbase = blk + wave*128;
    for (int chunk = 0; chunk < 2; ++chunk) {
        int4 my = rec[wbase + chunk*64 + lane];
        unsigned long long bal = __ballot(my.x >= 0);
        int nval = __popcll(bal);
        if (nval == 0) break;
        for (int i = 0; i < nval; ++i) {
            int srcv = __shfl(my.x, i);
            int dstv = __shfl(my.y, i) & 0x07FFFFFF;
            const float4* h4 = (const float4*)(hbuf + (size_t)srcv*64);
            float a0 = 0.f, a1 = 0.f, a2 = 0.f, a3 = 0.f;
            #pragma unroll
            for (int c = 0; c < 16; ++c) {
                float4 f = h4[c];
                a0 = fmaf(f.x, w[4*c+0], a0);
                a1 = fmaf(f.y, w[4*c+1], a1);
                a2 = fmaf(f.z, w[4*c+2], a2);
                a3 = fmaf(f.w, w[4*c+3], a3);
            }
            atomicMax(M + (size_t)dstv*64 + lane, encf((a0 + a1) + (a2 + a3)));
        }
    }
}

// ---------- K-merge: acc2 += sum over Gc planes of decode(Mr); re-zero planes ----------
__global__ void k_merge(unsigned* __restrict__ Mr, float* __restrict__ acc2,
                        size_t n, size_t planeElems, int Gc, int zeroNext)
{
    size_t gid = (size_t)blockIdx.x*blockDim.x + threadIdx.x;
    size_t stride = (size_t)gridDim.x*blockDim.x;
    for (size_t k = gid; k < n; k += stride) {
        float s = 0.f;
        for (int g = 0; g < Gc; ++g) {
            unsigned v = Mr[(size_t)g*planeElems + k];
            if (zeroNext) Mr[(size_t)g*planeElems + k] = 0u;
            if (v) s += decf(v);             // v==0 <=> empty (dst,rel) -> +0
        }
        acc2[k] += s;
    }
}

// ---------- K4: h2 = relu(acc2); o = relu(omega@Wo+bo); head ----------
__global__ __launch_bounds__(64) void k_final(
    const float* __restrict__ acc2, const float* __restrict__ omega,
    const float* __restrict__ Wo, const float* __restrict__ bo,
    const float* __restrict__ Wagg, const float* __restrict__ bagg,
    const float* __restrict__ Wc, const float* __restrict__ bc,
    float* __restrict__ out)
{
    int i = blockIdx.x, j = threadIdx.x;
    __shared__ __align__(16) float cS[128];
    float om0 = omega[2*i], om1 = omega[2*i+1];
    float oj = fmaxf(fmaf(om1, Wo[64+j], fmaf(om0, Wo[j], bo[j])), 0.f);
    float h2 = fmaxf(acc2[(size_t)i*64 + j], 0.f);
    cS[j] = h2;
    cS[64 + j] = oj;
    __syncthreads();
    float t = bagg[j];
    const float4* c4 = (const float4*)cS;
    #pragma unroll
    for (int c = 0; c < 32; ++c) {
        float4 f = c4[c];
        t = fmaf(f.x, Wagg[(4*c+0)*64+j], t);
        t = fmaf(f.y, Wagg[(4*c+1)*64+j], t);
        t = fmaf(f.z, Wagg[(4*c+2)*64+j], t);
        t = fmaf(f.w, Wagg[(4*c+3)*64+j], t);
    }
    t = fmaxf(t, 0.f);
    float part = t * Wc[j];
    #pragma unroll
    for (int off = 32; off; off >>= 1) part += __shfl_xor(part, off);
    if (j == 0) out[i] = tanhf(part + bc[0]) * 5.0f;
}

extern "C" void kernel_launch(void* const* d_in, const int* in_sizes, int n_in,
                              void* d_out, int out_size, void* d_ws, size_t ws_size,
                              hipStream_t stream)
{
    const float* x      = (const float*)d_in[0];
    const int*   ei     = (const int*)d_in[1];
    const float* ea     = (const float*)d_in[2];
    const int*   et     = (const int*)d_in[3];
    const float* omega  = (const float*)d_in[4];
    const float* Wn     = (const float*)d_in[5];
    const float* bn     = (const float*)d_in[6];
    const float* We     = (const float*)d_in[7];
    const float* be     = (const float*)d_in[8];
    const float* Wo     = (const float*)d_in[9];
    const float* bo     = (const float*)d_in[10];
    const float* W1     = (const float*)d_in[11];
    const float* Wroot1 = (const float*)d_in[12];
    const float* b1     = (const float*)d_in[13];
    const float* W2     = (const float*)d_in[14];
    const float* Wroot2 = (const float*)d_in[15];
    const float* b2     = (const float*)d_in[16];
    const float* Wagg   = (const float*)d_in[17];
    const float* bagg   = (const float*)d_in[18];
    const float* Wc     = (const float*)d_in[19];
    const float* bc     = (const float*)d_in[20];
    int N = in_sizes[0] / 3;
    int E = in_sizes[3];
    float* out = (float*)d_out;

    // ---- workspace layout ----
    int nwin   = (E + 511)/512 + 8;                    // window upper bound (8 segments, <512 pad each)
    int nslots = nwin * 512;
    char* p = (char*)d_ws;
    float* nbuf = (float*)p;  p += (size_t)N*64*4;     // n; reused as acc2
    float* acc1 = (float*)p;  p += (size_t)N*64*4;     // acc1 -> h
    int4*  rec  = (int4*)p;   p += (size_t)nslots*16;  // packed edge records
    int*   cnt  = (int*)p;    p += 8*4;
    int*   cursor = (int*)p;  p += 8*4;
    size_t off = (size_t)(p - (char*)d_ws);
    off = (off + 255) & ~(size_t)255;
    size_t planeElems = (size_t)N*64;
    size_t planeBytes = planeElems*4;
    size_t avail = (ws_size > off) ? (ws_size - off) : 0;
    int G = (int)(avail / planeBytes);
    if (G > 8) G = 8;
    if (G < 1) G = 1;                                  // ws_size >= ~103MB per R2/R3 evidence
    unsigned* Mr = (unsigned*)((char*)d_ws + off);     // [G, N, 64]
    float* acc2 = nbuf;                                // alias (n dead after k_edge1)

    k_encoder<<<N, 64, 0, stream>>>(x, Wn, bn, Wroot1, b1, nbuf, acc1);
    k_init<<<2048, 256, 0, stream>>>(Mr, rec, cnt, (size_t)G*planeElems, nslots);
    k_hist<<<1024, 256, 0, stream>>>(et, cnt, E);
    k_scan<<<1, 64, 0, stream>>>(cnt, cursor, 512);
    k_scatter<<<(E + 255)/256, 256, 0, stream>>>(ei, ea, et, cursor, rec, E);
    k_edge1<<<nwin, 256, 0, stream>>>(rec, nbuf, W1, We, be, acc1);
    k_hrow<<<N, 64, 0, stream>>>(acc1, acc2, Wroot2, b2);
    for (int g0 = 0; g0 < 8; g0 += G) {
        int Gc = (8 - g0 < G) ? (8 - g0) : G;
        k_edge2g<<<nwin, 256, 0, stream>>>(rec, acc1, W2, Mr, g0, Gc, planeElems);
        k_merge<<<1024, 256, 0, stream>>>(Mr, acc2, planeElems, planeElems, Gc,
                                          (g0 + Gc < 8) ? 1 : 0);
    }
    k_final<<<N, 64, 0, stream>>>(acc2, omega, Wo, bo, Wagg, bagg, Wc, bc, out);
}

// Round 5
// 2584.498 us; speedup vs baseline: 1.3919x; 1.0755x over previous
//
#include <hip/hip_runtime.h>
#include <cmath>

// ---------- helpers: order-preserving float<->uint for atomicMax ----------
// encf never returns 0 for non-NaN inputs, so 0 is the "empty" marker.
__device__ __forceinline__ unsigned encf(float f) {
    unsigned u = __float_as_uint(f);
    return (u & 0x80000000u) ? ~u : (u | 0x80000000u);
}
__device__ __forceinline__ float decf(unsigned v) {
    unsigned u = (v & 0x80000000u) ? (v ^ 0x80000000u) : ~v;
    return __uint_as_float(u);
}

// ---------- K0: encoder. one wave per node. lane = output dim ----------
__global__ __launch_bounds__(64) void k_encoder(
    const float* __restrict__ x,
    const float* __restrict__ Wn, const float* __restrict__ bn,
    const float* __restrict__ Wroot1, const float* __restrict__ b1,
    float* __restrict__ nbuf, float* __restrict__ acc1)
{
    int i = blockIdx.x;
    int j = threadIdx.x;
    __shared__ __align__(16) float nS[64];
    float x0 = x[3*i], x1 = x[3*i+1], x2 = x[3*i+2];
    float nj = fmaxf(fmaf(x2, Wn[128+j], fmaf(x1, Wn[64+j], fmaf(x0, Wn[j], bn[j]))), 0.f);
    size_t o64 = (size_t)i*64 + j;
    nbuf[o64] = nj;
    nS[j] = nj;
    __syncthreads();
    float acc = b1[j];
    const float4* n4 = (const float4*)nS;
    #pragma unroll
    for (int c = 0; c < 16; ++c) {
        float4 f = n4[c];
        acc = fmaf(f.x, Wroot1[(4*c+0)*64+j], acc);
        acc = fmaf(f.y, Wroot1[(4*c+1)*64+j], acc);
        acc = fmaf(f.z, Wroot1[(4*c+2)*64+j], acc);
        acc = fmaf(f.w, Wroot1[(4*c+3)*64+j], acc);
    }
    acc1[o64] = acc;
}

// ---------- K-init: zero Mr planes, rec=-1, cnt=0 ----------
__global__ void k_init(unsigned* __restrict__ Mr, int4* __restrict__ rec,
                       int* __restrict__ cnt, size_t mrn, int nslots)
{
    size_t gid = (size_t)blockIdx.x*blockDim.x + threadIdx.x;
    size_t stride = (size_t)gridDim.x*blockDim.x;
    uint4* M4 = (uint4*)Mr;
    size_t m4 = mrn >> 2;
    for (size_t k = gid; k < m4; k += stride) M4[k] = make_uint4(0,0,0,0);
    for (size_t k = gid; k < (size_t)nslots; k += stride) rec[k] = make_int4(-1,-1,-1,-1);
    if (gid < 8) cnt[gid] = 0;
}

// ---------- bucket edges by relation ----------
__global__ void k_hist(const int* __restrict__ et, int* __restrict__ cnt, int E)
{
    __shared__ int h[8];
    if (threadIdx.x < 8) h[threadIdx.x] = 0;
    __syncthreads();
    int gid = blockIdx.x*blockDim.x + threadIdx.x;
    int stride = gridDim.x*blockDim.x;
    for (int e = gid; e < E; e += stride) atomicAdd(&h[et[e]], 1);
    __syncthreads();
    if (threadIdx.x < 8) atomicAdd(&cnt[threadIdx.x], h[threadIdx.x]);
}

__global__ void k_scan(const int* __restrict__ cnt, int* __restrict__ cursor, int EPB)
{
    if (threadIdx.x == 0) {
        int o = 0;
        for (int r = 0; r < 8; ++r) {
            cursor[r] = o;
            int c = cnt[r];
            o += ((c + EPB - 1)/EPB)*EPB;   // pad each segment to EPB multiple
        }
    }
}

// scatter packed edge records: (src, dst|rel<<27, a0, a1)
__global__ void k_scatter(const int* __restrict__ ei, const float* __restrict__ ea,
                          const int* __restrict__ et, int* __restrict__ cursor,
                          int4* __restrict__ rec, int E)
{
    __shared__ int h[8];
    __shared__ int base8[8];
    if (threadIdx.x < 8) h[threadIdx.x] = 0;
    __syncthreads();
    int e = blockIdx.x*blockDim.x + threadIdx.x;
    int r = 0, lpos = 0;
    bool act = (e < E);
    if (act) { r = et[e]; lpos = atomicAdd(&h[r], 1); }
    __syncthreads();
    if (threadIdx.x < 8)
        base8[threadIdx.x] = (h[threadIdx.x] > 0) ? atomicAdd(&cursor[threadIdx.x], h[threadIdx.x]) : 0;
    __syncthreads();
    if (act) {
        int4 v = make_int4(ei[e], ei[E + e] | (r << 27),
                           __float_as_int(ea[2*e]), __float_as_int(ea[2*e + 1]));
        rec[base8[r] + lpos] = v;
    }
}

// ---------- K1: layer-1 edge pass. 256 threads = 4 waves; block = 256-edge window
// (4 tiles of 64, one relation). lane = EDGE; wave w covers out-dims [16w,16w+16).
// Weights are wave-uniform -> SGPR s_loads (never VGPR arrays). Feature tile in LDS.
__global__ __launch_bounds__(256, 4) void k_edge1(
    const int4* __restrict__ rec, const float* __restrict__ nbuf,
    const float* __restrict__ W1, const float* __restrict__ We,
    const float* __restrict__ be, float* __restrict__ acc1)
{
    __shared__ float fS[96*64];     // feat tile k-major [96][64]; reused as accS [64][65]
    __shared__ int dstS[64];
    int lane = threadIdx.x & 63;
    int wave = threadIdx.x >> 6;
    long blk = (long)blockIdx.x * 256;
    int4 h0 = rec[blk];
    if (h0.x < 0) return;                            // whole window is padding
    int rel = __builtin_amdgcn_readfirstlane(h0.y >> 27);
    const float* Wr = W1 + (size_t)rel*96*64 + 16*wave;  // uniform base for this wave's j-slice
    for (int tile = 0; tile < 4; ++tile) {
        int4 my = rec[blk + tile*64 + lane];
        unsigned long long bal = __ballot(my.x >= 0);
        int nval = __popcll(bal);
        if (nval == 0) break;                        // padding contiguous at tail
        int srcv = (my.x < 0) ? 0 : my.x;
        // --- gather: wave w stages feature rows [16w,16w+16) + e-rows [8w,8w+8) ---
        {
            const float4* row = (const float4*)(nbuf + (size_t)srcv*64);
            #pragma unroll
            for (int c = 0; c < 4; ++c) {
                float4 f = row[4*wave + c];
                int k0 = 16*wave + 4*c;
                fS[(k0+0)*64 + lane] = f.x;
                fS[(k0+1)*64 + lane] = f.y;
                fS[(k0+2)*64 + lane] = f.z;
                fS[(k0+3)*64 + lane] = f.w;
            }
            float a0 = __int_as_float(my.z), a1 = __int_as_float(my.w);
            #pragma unroll
            for (int m8 = 0; m8 < 8; ++m8) {
                int m = 8*wave + m8;                 // uniform -> We/be scalar loads
                fS[(64+m)*64 + lane] =
                    fmaxf(fmaf(a1, We[32+m], fmaf(a0, We[m], be[m])), 0.f);
            }
            dstS[lane] = my.y & 0x07FFFFFF;          // idempotent across waves
        }
        __syncthreads();
        // --- compute: lane = edge; 16 accumulators; W operand uniform (SGPR) ---
        float acc[16];
        #pragma unroll
        for (int jj = 0; jj < 16; ++jj) acc[jj] = 0.f;
        #pragma unroll 4
        for (int k = 0; k < 96; ++k) {
            float fk = fS[k*64 + lane];
            #pragma unroll
            for (int jj = 0; jj < 16; ++jj)
                acc[jj] = fmaf(fk, Wr[k*64 + jj], acc[jj]);
        }
        __syncthreads();                             // feat reads done; reuse fS as accS
        #pragma unroll
        for (int jj = 0; jj < 16; ++jj)
            fS[lane*65 + 16*wave + jj] = acc[jj];
        __syncthreads();
        // --- scatter: wave w flushes edges [16w,16w+16), coalesced 256B atomics ---
        for (int t = 0; t < 16; ++t) {
            int e = 16*wave + t;
            if (e >= nval) break;
            int dste = dstS[e];
            atomicAdd(acc1 + (size_t)dste*64 + lane, fS[e*65 + lane]);
        }
        __syncthreads();                             // before next tile reuses fS
    }
}

// ---------- K2: fused relu + root2. acc1 -> h (in place); acc2 = h@Wroot2+b2 ----------
__global__ __launch_bounds__(64) void k_hrow(
    float* __restrict__ acc1, float* __restrict__ acc2,
    const float* __restrict__ Wroot2, const float* __restrict__ b2)
{
    int i = blockIdx.x, j = threadIdx.x;
    __shared__ __align__(16) float hS[64];
    size_t o64 = (size_t)i*64 + j;
    float h = fmaxf(acc1[o64], 0.f);
    acc1[o64] = h;
    hS[j] = h;
    __syncthreads();
    float acc = b2[j];
    const float4* h4 = (const float4*)hS;
    #pragma unroll
    for (int c = 0; c < 16; ++c) {
        float4 f = h4[c];
        acc = fmaf(f.x, Wroot2[(4*c+0)*64+j], acc);
        acc = fmaf(f.y, Wroot2[(4*c+1)*64+j], acc);
        acc = fmaf(f.z, Wroot2[(4*c+2)*64+j], acc);
        acc = fmaf(f.w, Wroot2[(4*c+3)*64+j], acc);
    }
    acc2[o64] = acc;
}

// ---------- K3: layer-2 edge pass, relations [g0,g0+Gc). Same lane=edge/SGPR design ----------
__global__ __launch_bounds__(256, 4) void k_edge2g(
    const int4* __restrict__ rec, const float* __restrict__ hbuf,
    const float* __restrict__ W2, unsigned* __restrict__ Mr,
    int g0, int Gc, size_t planeElems)
{
    __shared__ float fS[64*65];     // feat tile [64][64] + accS overlay [64][65]
    __shared__ int dstS[64];
    int lane = threadIdx.x & 63;
    int wave = threadIdx.x >> 6;
    long blk = (long)blockIdx.x * 256;
    int4 h0 = rec[blk];
    if (h0.x < 0) return;
    int rel = __builtin_amdgcn_readfirstlane(h0.y >> 27);
    int p = rel - g0;
    if (p < 0 || p >= Gc) return;                    // not in this pass's relation group
    unsigned* M = Mr + (size_t)p * planeElems;
    const float* Wr = W2 + (size_t)rel*64*64 + 16*wave;
    for (int tile = 0; tile < 4; ++tile) {
        int4 my = rec[blk + tile*64 + lane];
        unsigned long long bal = __ballot(my.x >= 0);
        int nval = __popcll(bal);
        if (nval == 0) break;
        int srcv = (my.x < 0) ? 0 : my.x;
        {
            const float4* row = (const float4*)(hbuf + (size_t)srcv*64);
            #pragma unroll
            for (int c = 0; c < 4; ++c) {
                float4 f = row[4*wave + c];
                int k0 = 16*wave + 4*c;
                fS[(k0+0)*64 + lane] = f.x;
                fS[(k0+1)*64 + lane] = f.y;
                fS[(k0+2)*64 + lane] = f.z;
                fS[(k0+3)*64 + lane] = f.w;
            }
            dstS[lane] = my.y & 0x07FFFFFF;
        }
        __syncthreads();
        float acc[16];
        #pragma unroll
        for (int jj = 0; jj < 16; ++jj) acc[jj] = 0.f;
        #pragma unroll 4
        for (int k = 0; k < 64; ++k) {
            float fk = fS[k*64 + lane];
            #pragma unroll
            for (int jj = 0; jj < 16; ++jj)
                acc[jj] = fmaf(fk, Wr[k*64 + jj], acc[jj]);
        }
        __syncthreads();
        #pragma unroll
        for (int jj = 0; jj < 16; ++jj)
            fS[lane*65 + 16*wave + jj] = acc[jj];
        __syncthreads();
        for (int t = 0; t < 16; ++t) {
            int e = 16*wave + t;
            if (e >= nval) break;
            int dste = dstS[e];
            atomicMax(M + (size_t)dste*64 + lane, encf(fS[e*65 + lane]));
        }
        __syncthreads();
    }
}

// ---------- K-merge: acc2 += sum over Gc planes of decode(Mr); re-zero planes ----------
__global__ void k_merge(unsigned* __restrict__ Mr, float* __restrict__ acc2,
                        size_t n, size_t planeElems, int Gc, int zeroNext)
{
    size_t gid = (size_t)blockIdx.x*blockDim.x + threadIdx.x;
    size_t stride = (size_t)gridDim.x*blockDim.x;
    for (size_t k = gid; k < n; k += stride) {
        float s = 0.f;
        for (int g = 0; g < Gc; ++g) {
            unsigned v = Mr[(size_t)g*planeElems + k];
            if (zeroNext) Mr[(size_t)g*planeElems + k] = 0u;
            if (v) s += decf(v);             // v==0 <=> empty (dst,rel) -> +0
        }
        acc2[k] += s;
    }
}

// ---------- K4: h2 = relu(acc2); o = relu(omega@Wo+bo); head ----------
__global__ __launch_bounds__(64) void k_final(
    const float* __restrict__ acc2, const float* __restrict__ omega,
    const float* __restrict__ Wo, const float* __restrict__ bo,
    const float* __restrict__ Wagg, const float* __restrict__ bagg,
    const float* __restrict__ Wc, const float* __restrict__ bc,
    float* __restrict__ out)
{
    int i = blockIdx.x, j = threadIdx.x;
    __shared__ __align__(16) float cS[128];
    float om0 = omega[2*i], om1 = omega[2*i+1];
    float oj = fmaxf(fmaf(om1, Wo[64+j], fmaf(om0, Wo[j], bo[j])), 0.f);
    float h2 = fmaxf(acc2[(size_t)i*64 + j], 0.f);
    cS[j] = h2;
    cS[64 + j] = oj;
    __syncthreads();
    float t = bagg[j];
    const float4* c4 = (const float4*)cS;
    #pragma unroll
    for (int c = 0; c < 32; ++c) {
        float4 f = c4[c];
        t = fmaf(f.x, Wagg[(4*c+0)*64+j], t);
        t = fmaf(f.y, Wagg[(4*c+1)*64+j], t);
        t = fmaf(f.z, Wagg[(4*c+2)*64+j], t);
        t = fmaf(f.w, Wagg[(4*c+3)*64+j], t);
    }
    t = fmaxf(t, 0.f);
    float part = t * Wc[j];
    #pragma unroll
    for (int off = 32; off; off >>= 1) part += __shfl_xor(part, off);
    if (j == 0) out[i] = tanhf(part + bc[0]) * 5.0f;
}

extern "C" void kernel_launch(void* const* d_in, const int* in_sizes, int n_in,
                              void* d_out, int out_size, void* d_ws, size_t ws_size,
                              hipStream_t stream)
{
    const float* x      = (const float*)d_in[0];
    const int*   ei     = (const int*)d_in[1];
    const float* ea     = (const float*)d_in[2];
    const int*   et     = (const int*)d_in[3];
    const float* omega  = (const float*)d_in[4];
    const float* Wn     = (const float*)d_in[5];
    const float* bn     = (const float*)d_in[6];
    const float* We     = (const float*)d_in[7];
    const float* be     = (const float*)d_in[8];
    const float* Wo     = (const float*)d_in[9];
    const float* bo     = (const float*)d_in[10];
    const float* W1     = (const float*)d_in[11];
    const float* Wroot1 = (const float*)d_in[12];
    const float* b1     = (const float*)d_in[13];
    const float* W2     = (const float*)d_in[14];
    const float* Wroot2 = (const float*)d_in[15];
    const float* b2     = (const float*)d_in[16];
    const float* Wagg   = (const float*)d_in[17];
    const float* bagg   = (const float*)d_in[18];
    const float* Wc     = (const float*)d_in[19];
    const float* bc     = (const float*)d_in[20];
    int N = in_sizes[0] / 3;
    int E = in_sizes[3];
    float* out = (float*)d_out;

    // ---- workspace layout ----
    int nwin   = (E + 255)/256 + 8;                    // 256-edge windows (8 segments, <256 pad each)
    int nslots = nwin * 256;
    char* p = (char*)d_ws;
    float* nbuf = (float*)p;  p += (size_t)N*64*4;     // n; reused as acc2
    float* acc1 = (float*)p;  p += (size_t)N*64*4;     // acc1 -> h
    int4*  rec  = (int4*)p;   p += (size_t)nslots*16;  // packed edge records
    int*   cnt  = (int*)p;    p += 8*4;
    int*   cursor = (int*)p;  p += 8*4;
    size_t off = (size_t)(p - (char*)d_ws);
    off = (off + 255) & ~(size_t)255;
    size_t planeElems = (size_t)N*64;
    size_t planeBytes = planeElems*4;
    size_t avail = (ws_size > off) ? (ws_size - off) : 0;
    int G = (int)(avail / planeBytes);
    if (G > 8) G = 8;
    if (G < 1) G = 1;
    unsigned* Mr = (unsigned*)((char*)d_ws + off);     // [G, N, 64]
    float* acc2 = nbuf;                                // alias (n dead after k_edge1)

    k_encoder<<<N, 64, 0, stream>>>(x, Wn, bn, Wroot1, b1, nbuf, acc1);
    k_init<<<2048, 256, 0, stream>>>(Mr, rec, cnt, (size_t)G*planeElems, nslots);
    k_hist<<<1024, 256, 0, stream>>>(et, cnt, E);
    k_scan<<<1, 64, 0, stream>>>(cnt, cursor, 256);
    k_scatter<<<(E + 255)/256, 256, 0, stream>>>(ei, ea, et, cursor, rec, E);
    k_edge1<<<nwin, 256, 0, stream>>>(rec, nbuf, W1, We, be, acc1);
    k_hrow<<<N, 64, 0, stream>>>(acc1, acc2, Wroot2, b2);
    for (int g0 = 0; g0 < 8; g0 += G) {
        int Gc = (8 - g0 < G) ? (8 - g0) : G;
        k_edge2g<<<nwin, 256, 0, stream>>>(rec, acc1, W2, Mr, g0, Gc, planeElems);
        k_merge<<<1024, 256, 0, stream>>>(Mr, acc2, planeElems, planeElems, Gc,
                                          (g0 + Gc < 8) ? 1 : 0);
    }
    k_final<<<N, 64, 0, stream>>>(acc2, omega, Wo, bo, Wagg, bagg, Wc, bc, out);
}

// Round 6
// 1596.329 us; speedup vs baseline: 2.2535x; 1.6190x over previous
//
#include <hip/hip_runtime.h>
#include <cmath>

typedef __attribute__((ext_vector_type(8))) short short8;
typedef __attribute__((ext_vector_type(4))) float floatx4;

// ---------- helpers ----------
__device__ __forceinline__ unsigned encf(float f) {
    unsigned u = __float_as_uint(f);
    return (u & 0x80000000u) ? ~u : (u | 0x80000000u);
}
__device__ __forceinline__ float decf(unsigned v) {
    unsigned u = (v & 0x80000000u) ? (v ^ 0x80000000u) : ~v;
    return __uint_as_float(u);
}
// round-to-nearest-even fp32 -> bf16 bits
__device__ __forceinline__ unsigned short rnbf(float f) {
    unsigned u = __float_as_uint(f);
    u += 0x7fffu + ((u >> 16) & 1u);
    return (unsigned short)(u >> 16);
}
__device__ __forceinline__ float bf2f(unsigned short h) {
    return __uint_as_float(((unsigned)h) << 16);
}

// ---------- K0: encoder. one wave per node ----------
__global__ __launch_bounds__(64) void k_encoder(
    const float* __restrict__ x,
    const float* __restrict__ Wn, const float* __restrict__ bn,
    const float* __restrict__ Wroot1, const float* __restrict__ b1,
    float* __restrict__ nbuf, float* __restrict__ acc1)
{
    int i = blockIdx.x;
    int j = threadIdx.x;
    __shared__ __align__(16) float nS[64];
    float x0 = x[3*i], x1 = x[3*i+1], x2 = x[3*i+2];
    float nj = fmaxf(fmaf(x2, Wn[128+j], fmaf(x1, Wn[64+j], fmaf(x0, Wn[j], bn[j]))), 0.f);
    size_t o64 = (size_t)i*64 + j;
    nbuf[o64] = nj;
    nS[j] = nj;
    __syncthreads();
    float acc = b1[j];
    const float4* n4 = (const float4*)nS;
    #pragma unroll
    for (int c = 0; c < 16; ++c) {
        float4 f = n4[c];
        acc = fmaf(f.x, Wroot1[(4*c+0)*64+j], acc);
        acc = fmaf(f.y, Wroot1[(4*c+1)*64+j], acc);
        acc = fmaf(f.z, Wroot1[(4*c+2)*64+j], acc);
        acc = fmaf(f.w, Wroot1[(4*c+3)*64+j], acc);
    }
    acc1[o64] = acc;
}

// ---------- init: rec=-1, cnt=0 ----------
__global__ void k_init(int4* __restrict__ rec, int* __restrict__ cnt, int nslots)
{
    size_t gid = (size_t)blockIdx.x*blockDim.x + threadIdx.x;
    size_t stride = (size_t)gridDim.x*blockDim.x;
    for (size_t k = gid; k < (size_t)nslots; k += stride) rec[k] = make_int4(-1,-1,-1,-1);
    if (gid < 8) cnt[gid] = 0;
}

// ---------- zero a region (uint4 granularity) ----------
__global__ void k_zero(uint4* __restrict__ dst, size_t n16)
{
    size_t gid = (size_t)blockIdx.x*blockDim.x + threadIdx.x;
    size_t stride = (size_t)gridDim.x*blockDim.x;
    for (size_t k = gid; k < n16; k += stride) dst[k] = make_uint4(0,0,0,0);
}

// ---------- bucket edges by relation ----------
__global__ void k_hist(const int* __restrict__ et, int* __restrict__ cnt, int E)
{
    __shared__ int h[8];
    if (threadIdx.x < 8) h[threadIdx.x] = 0;
    __syncthreads();
    int gid = blockIdx.x*blockDim.x + threadIdx.x;
    int stride = gridDim.x*blockDim.x;
    for (int e = gid; e < E; e += stride) atomicAdd(&h[et[e]], 1);
    __syncthreads();
    if (threadIdx.x < 8) atomicAdd(&cnt[threadIdx.x], h[threadIdx.x]);
}

__global__ void k_scan(const int* __restrict__ cnt, int* __restrict__ cursor, int EPB)
{
    if (threadIdx.x == 0) {
        int o = 0;
        for (int r = 0; r < 8; ++r) {
            cursor[r] = o;
            int c = cnt[r];
            o += ((c + EPB - 1)/EPB)*EPB;
        }
    }
}

__global__ void k_scatter(const int* __restrict__ ei, const float* __restrict__ ea,
                          const int* __restrict__ et, int* __restrict__ cursor,
                          int4* __restrict__ rec, int E)
{
    __shared__ int h[8];
    __shared__ int base8[8];
    if (threadIdx.x < 8) h[threadIdx.x] = 0;
    __syncthreads();
    int e = blockIdx.x*blockDim.x + threadIdx.x;
    int r = 0, lpos = 0;
    bool act = (e < E);
    if (act) { r = et[e]; lpos = atomicAdd(&h[r], 1); }
    __syncthreads();
    if (threadIdx.x < 8)
        base8[threadIdx.x] = (h[threadIdx.x] > 0) ? atomicAdd(&cursor[threadIdx.x], h[threadIdx.x]) : 0;
    __syncthreads();
    if (act) {
        int4 v = make_int4(ei[e], ei[E + e] | (r << 27),
                           __float_as_int(ea[2*e]), __float_as_int(ea[2*e + 1]));
        rec[base8[r] + lpos] = v;
    }
}

// ---------- pack weights into MFMA B-fragment order, split bf16 hi/lo ----------
// units: [0,16)  = W1A (layer1 n-part), rel=u>>1, ks=u&1, rows 0..63 of W1[rel]
//        [16,32) = W2   (layer2),       rel=(u-16)>>1, ks, rows 0..63 of W2[rel]
//        [32,40) = W1B (layer1 e-part), rel=u-32, ks=0, rows 64..95 of W1[rel]
// entry(unit, jt, lane): 16 ushorts: [0..7]=hi bf16, [8..15]=lo bf16
// element i: W[krow(i)][jt*16 + (lane&15)], krow = ksbase + (lane>>4)*8 + i
__global__ __launch_bounds__(64) void k_wpack(
    const float* __restrict__ W1, const float* __restrict__ W2,
    unsigned short* __restrict__ wpk)
{
    int unit = blockIdx.x >> 2;
    int jt = blockIdx.x & 3;
    int lane = threadIdx.x;
    const float* Wb;
    int kbase;
    if (unit < 16) {
        Wb = W1 + (size_t)(unit >> 1)*96*64;
        kbase = (unit & 1)*32;
    } else if (unit < 32) {
        Wb = W2 + (size_t)((unit - 16) >> 1)*64*64;
        kbase = ((unit - 16) & 1)*32;
    } else {
        Wb = W1 + (size_t)(unit - 32)*96*64;
        kbase = 64;
    }
    int j = jt*16 + (lane & 15);
    size_t base = (((size_t)unit*4 + jt)*64 + lane)*16;
    #pragma unroll
    for (int i = 0; i < 8; ++i) {
        int k = kbase + (lane >> 4)*8 + i;
        float f = Wb[(size_t)k*64 + j];
        unsigned short hi = rnbf(f);
        unsigned short lo = rnbf(f - bf2f(hi));
        wpk[base + i] = hi;
        wpk[base + 8 + i] = lo;
    }
}

// ---------- dense GEMM via MFMA split-bf16: out_p[n][j] = sum_k F[n][k]*W[rel][k][j]
// F: [N,64] fp32. 256 thr = 4 waves, wave = 16-node tile. K=64 (2 K-steps).
__global__ __launch_bounds__(256) void k_vgemm(
    const float* __restrict__ F, const unsigned short* __restrict__ wpk,
    int unitBase, int g0, int Gc, float* __restrict__ Vpool,
    size_t plane, int N)
{
    int lane = threadIdx.x & 63;
    int wave = threadIdx.x >> 6;
    int n0 = blockIdx.x*64 + 16*wave;
    int m = lane & 15, q = lane >> 4;
    int node = n0 + m;
    if (node >= N) node = N - 1;                 // clamp load; stores guarded
    const float4* Fr = (const float4*)(F + (size_t)node*64);
    short8 ah[2], al[2];
    #pragma unroll
    for (int ks = 0; ks < 2; ++ks) {
        float4 u0 = Fr[ks*8 + q*2];
        float4 u1 = Fr[ks*8 + q*2 + 1];
        float fv[8] = {u0.x,u0.y,u0.z,u0.w,u1.x,u1.y,u1.z,u1.w};
        #pragma unroll
        for (int i = 0; i < 8; ++i) {
            unsigned short hb = rnbf(fv[i]);
            ah[ks][i] = (short)hb;
            al[ks][i] = (short)rnbf(fv[i] - bf2f(hb));
        }
    }
    for (int p = 0; p < Gc; ++p) {
        int rel = g0 + p;
        floatx4 acc[4];
        #pragma unroll
        for (int jt = 0; jt < 4; ++jt) acc[jt] = (floatx4){0.f,0.f,0.f,0.f};
        #pragma unroll
        for (int ks = 0; ks < 2; ++ks) {
            int unit = unitBase + rel*2 + ks;
            #pragma unroll
            for (int jt = 0; jt < 4; ++jt) {
                const unsigned short* qp = wpk + (((size_t)unit*4 + jt)*64 + lane)*16;
                short8 bh = *(const short8*)qp;
                short8 bl = *(const short8*)(qp + 8);
                acc[jt] = __builtin_amdgcn_mfma_f32_16x16x32_bf16(ah[ks], bh, acc[jt], 0,0,0);
                acc[jt] = __builtin_amdgcn_mfma_f32_16x16x32_bf16(ah[ks], bl, acc[jt], 0,0,0);
                acc[jt] = __builtin_amdgcn_mfma_f32_16x16x32_bf16(al[ks], bh, acc[jt], 0,0,0);
            }
        }
        float* Vp = Vpool + (size_t)p*plane;
        #pragma unroll
        for (int jt = 0; jt < 4; ++jt) {
            #pragma unroll
            for (int t = 0; t < 4; ++t) {
                int row = n0 + q*4 + t;          // D: col=lane&15, row=q*4+reg
                if (row < N) Vp[(size_t)row*64 + jt*16 + m] = acc[jt][t];
            }
        }
    }
}

// ---------- Se GEMM via MFMA: acc1[n][j] += sum_m Se_p[n][m]*W1B[rel][m][j], K=32 ----------
__global__ __launch_bounds__(256) void k_segemm(
    const float* __restrict__ Sepool, const unsigned short* __restrict__ wpk,
    int g0, int Gc, float* __restrict__ acc1, size_t half, int N)
{
    int lane = threadIdx.x & 63;
    int wave = threadIdx.x >> 6;
    int n0 = blockIdx.x*64 + 16*wave;
    int m = lane & 15, q = lane >> 4;
    int node = n0 + m;
    if (node >= N) node = N - 1;
    for (int p = 0; p < Gc; ++p) {
        int rel = g0 + p;
        const float4* Fr = (const float4*)(Sepool + (size_t)p*half + (size_t)node*32);
        float4 u0 = Fr[q*2];
        float4 u1 = Fr[q*2 + 1];
        float fv[8] = {u0.x,u0.y,u0.z,u0.w,u1.x,u1.y,u1.z,u1.w};
        short8 ah, al;
        #pragma unroll
        for (int i = 0; i < 8; ++i) {
            unsigned short hb = rnbf(fv[i]);
            ah[i] = (short)hb;
            al[i] = (short)rnbf(fv[i] - bf2f(hb));
        }
        floatx4 acc[4];
        #pragma unroll
        for (int jt = 0; jt < 4; ++jt) acc[jt] = (floatx4){0.f,0.f,0.f,0.f};
        int unit = 32 + rel;
        #pragma unroll
        for (int jt = 0; jt < 4; ++jt) {
            const unsigned short* qp = wpk + (((size_t)unit*4 + jt)*64 + lane)*16;
            short8 bh = *(const short8*)qp;
            short8 bl = *(const short8*)(qp + 8);
            acc[jt] = __builtin_amdgcn_mfma_f32_16x16x32_bf16(ah, bh, acc[jt], 0,0,0);
            acc[jt] = __builtin_amdgcn_mfma_f32_16x16x32_bf16(ah, bl, acc[jt], 0,0,0);
            acc[jt] = __builtin_amdgcn_mfma_f32_16x16x32_bf16(al, bh, acc[jt], 0,0,0);
        }
        #pragma unroll
        for (int jt = 0; jt < 4; ++jt) {
            #pragma unroll
            for (int t = 0; t < 4; ++t) {
                int row = n0 + q*4 + t;
                if (row < N) acc1[(size_t)row*64 + jt*16 + m] += acc[jt][t];
            }
        }
    }
}

// ---------- layer-1 edge pass: pure streaming. acc1[dst]+=V_p[src]; Se_p[dst]+=e ----------
__global__ __launch_bounds__(256) void k_edge1s(
    const int4* __restrict__ rec, const float* __restrict__ Vpool,
    float* __restrict__ Sepool, float* __restrict__ acc1,
    const float* __restrict__ We, const float* __restrict__ be,
    int g0, int Gc, size_t plane, size_t half)
{
    long blk = (long)blockIdx.x * 256;
    int4 h0 = rec[blk];
    if (h0.x < 0) return;
    int rel = __builtin_amdgcn_readfirstlane(h0.y >> 27);
    int p = rel - g0;
    if (p < 0 || p >= Gc) return;
    const float* Vp = Vpool + (size_t)p*plane;
    float* Sep = Sepool + (size_t)p*half;
    int lane = threadIdx.x & 63;
    int wv = __builtin_amdgcn_readfirstlane(threadIdx.x >> 6);
    int4 my = rec[blk + wv*64 + lane];
    unsigned long long bal = __ballot(my.x >= 0);
    int nval = __popcll(bal);
    float we0 = We[lane & 31], we1 = We[32 + (lane & 31)], bev = be[lane & 31];
    for (int i = 0; i < nval; ++i) {
        int src = __shfl(my.x, i);
        int dv  = __shfl(my.y, i) & 0x07FFFFFF;
        float a0 = __int_as_float(__shfl(my.z, i));
        float a1 = __int_as_float(__shfl(my.w, i));
        float v = Vp[(size_t)src*64 + lane];
        float ev = fmaxf(fmaf(a1, we1, fmaf(a0, we0, bev)), 0.f);
        atomicAdd(acc1 + (size_t)dv*64 + lane, v);
        if (lane < 32) atomicAdd(Sep + (size_t)dv*32 + lane, ev);
    }
}

// ---------- fused relu + root2: acc1->h in place; acc2 = h@Wroot2+b2 ----------
__global__ __launch_bounds__(64) void k_hrow(
    float* __restrict__ acc1, float* __restrict__ acc2,
    const float* __restrict__ Wroot2, const float* __restrict__ b2)
{
    int i = blockIdx.x, j = threadIdx.x;
    __shared__ __align__(16) float hS[64];
    size_t o64 = (size_t)i*64 + j;
    float h = fmaxf(acc1[o64], 0.f);
    acc1[o64] = h;
    hS[j] = h;
    __syncthreads();
    float acc = b2[j];
    const float4* h4 = (const float4*)hS;
    #pragma unroll
    for (int c = 0; c < 16; ++c) {
        float4 f = h4[c];
        acc = fmaf(f.x, Wroot2[(4*c+0)*64+j], acc);
        acc = fmaf(f.y, Wroot2[(4*c+1)*64+j], acc);
        acc = fmaf(f.z, Wroot2[(4*c+2)*64+j], acc);
        acc = fmaf(f.w, Wroot2[(4*c+3)*64+j], acc);
    }
    acc2[o64] = acc;
}

// ---------- layer-2 edge pass: pure streaming atomicMax of U_p[src] into Mr_p[dst] ----------
__global__ __launch_bounds__(256) void k_edge2s(
    const int4* __restrict__ rec, const float* __restrict__ Upool,
    unsigned* __restrict__ Mrpool, int g0, int Gc, size_t plane)
{
    long blk = (long)blockIdx.x * 256;
    int4 h0 = rec[blk];
    if (h0.x < 0) return;
    int rel = __builtin_amdgcn_readfirstlane(h0.y >> 27);
    int p = rel - g0;
    if (p < 0 || p >= Gc) return;
    const float* Up = Upool + (size_t)p*plane;
    unsigned* Mp = Mrpool + (size_t)p*plane;
    int lane = threadIdx.x & 63;
    int wv = __builtin_amdgcn_readfirstlane(threadIdx.x >> 6);
    int4 my = rec[blk + wv*64 + lane];
    unsigned long long bal = __ballot(my.x >= 0);
    int nval = __popcll(bal);
    for (int i = 0; i < nval; ++i) {
        int src = __shfl(my.x, i);
        int dv  = __shfl(my.y, i) & 0x07FFFFFF;
        float v = Up[(size_t)src*64 + lane];
        atomicMax(Mp + (size_t)dv*64 + lane, encf(v));
    }
}

// ---------- merge: acc2 += sum over Gc planes of decode(Mr) ----------
__global__ void k_merge(const unsigned* __restrict__ Mr, float* __restrict__ acc2,
                        size_t n, size_t plane, int Gc)
{
    size_t gid = (size_t)blockIdx.x*blockDim.x + threadIdx.x;
    size_t stride = (size_t)gridDim.x*blockDim.x;
    for (size_t k = gid; k < n; k += stride) {
        float s = 0.f;
        for (int g = 0; g < Gc; ++g) {
            unsigned v = Mr[(size_t)g*plane + k];
            if (v) s += decf(v);
        }
        acc2[k] += s;
    }
}

// ---------- head ----------
__global__ __launch_bounds__(64) void k_final(
    const float* __restrict__ acc2, const float* __restrict__ omega,
    const float* __restrict__ Wo, const float* __restrict__ bo,
    const float* __restrict__ Wagg, const float* __restrict__ bagg,
    const float* __restrict__ Wc, const float* __restrict__ bc,
    float* __restrict__ out)
{
    int i = blockIdx.x, j = threadIdx.x;
    __shared__ __align__(16) float cS[128];
    float om0 = omega[2*i], om1 = omega[2*i+1];
    float oj = fmaxf(fmaf(om1, Wo[64+j], fmaf(om0, Wo[j], bo[j])), 0.f);
    float h2 = fmaxf(acc2[(size_t)i*64 + j], 0.f);
    cS[j] = h2;
    cS[64 + j] = oj;
    __syncthreads();
    float t = bagg[j];
    const float4* c4 = (const float4*)cS;
    #pragma unroll
    for (int c = 0; c < 32; ++c) {
        float4 f = c4[c];
        t = fmaf(f.x, Wagg[(4*c+0)*64+j], t);
        t = fmaf(f.y, Wagg[(4*c+1)*64+j], t);
        t = fmaf(f.z, Wagg[(4*c+2)*64+j], t);
        t = fmaf(f.w, Wagg[(4*c+3)*64+j], t);
    }
    t = fmaxf(t, 0.f);
    float part = t * Wc[j];
    #pragma unroll
    for (int off = 32; off; off >>= 1) part += __shfl_xor(part, off);
    if (j == 0) out[i] = tanhf(part + bc[0]) * 5.0f;
}

extern "C" void kernel_launch(void* const* d_in, const int* in_sizes, int n_in,
                              void* d_out, int out_size, void* d_ws, size_t ws_size,
                              hipStream_t stream)
{
    const float* x      = (const float*)d_in[0];
    const int*   ei     = (const int*)d_in[1];
    const float* ea     = (const float*)d_in[2];
    const int*   et     = (const int*)d_in[3];
    const float* omega  = (const float*)d_in[4];
    const float* Wn     = (const float*)d_in[5];
    const float* bn     = (const float*)d_in[6];
    const float* We     = (const float*)d_in[7];
    const float* be     = (const float*)d_in[8];
    const float* Wo     = (const float*)d_in[9];
    const float* bo     = (const float*)d_in[10];
    const float* W1     = (const float*)d_in[11];
    const float* Wroot1 = (const float*)d_in[12];
    const float* b1     = (const float*)d_in[13];
    const float* W2     = (const float*)d_in[14];
    const float* Wroot2 = (const float*)d_in[15];
    const float* b2     = (const float*)d_in[16];
    const float* Wagg   = (const float*)d_in[17];
    const float* bagg   = (const float*)d_in[18];
    const float* Wc     = (const float*)d_in[19];
    const float* bc     = (const float*)d_in[20];
    int N = in_sizes[0] / 3;
    int E = in_sizes[3];
    float* out = (float*)d_out;

    // ---- workspace layout ----
    int nwin   = (E + 255)/256 + 8;
    int nslots = nwin * 256;
    char* pp = (char*)d_ws;
    float* nbuf = (float*)pp;  pp += (size_t)N*64*4;       // n; reused as acc2
    float* acc1 = (float*)pp;  pp += (size_t)N*64*4;       // acc1 -> h
    int4*  rec  = (int4*)pp;   pp += (size_t)nslots*16;
    int*   cnt  = (int*)pp;    pp += 8*4;
    int*   cursor = (int*)pp;  pp += 8*4;
    unsigned short* wpk = (unsigned short*)pp; pp += (size_t)40*4*64*16*2;  // 320KB
    size_t off = (size_t)(pp - (char*)d_ws);
    off = (off + 255) & ~(size_t)255;
    size_t planeElems = (size_t)N*64;
    size_t planeBytes = planeElems*4;
    size_t halfElems  = (size_t)N*32;
    size_t halfBytes  = halfElems*4;
    size_t avail = (ws_size > off) ? (ws_size - off) : 0;
    int G1 = (int)(avail / (planeBytes + halfBytes));  // per-rel: V plane + Se half
    int G2 = (int)(avail / (2*planeBytes));            // per-rel: U plane + Mr plane
    if (G1 > 8) G1 = 8; if (G1 < 1) G1 = 1;
    if (G2 > 8) G2 = 8; if (G2 < 1) G2 = 1;
    float*    poolF = (float*)((char*)d_ws + off);
    float*    Vpool = poolF;
    float*    Sepool = poolF + (size_t)G1*planeElems;
    float*    Upool = poolF;
    unsigned* Mrpool = (unsigned*)(poolF + (size_t)G2*planeElems);
    float* acc2 = nbuf;

    k_encoder<<<N, 64, 0, stream>>>(x, Wn, bn, Wroot1, b1, nbuf, acc1);
    k_init<<<1024, 256, 0, stream>>>(rec, cnt, nslots);
    k_hist<<<1024, 256, 0, stream>>>(et, cnt, E);
    k_scan<<<1, 64, 0, stream>>>(cnt, cursor, 256);
    k_scatter<<<(E + 255)/256, 256, 0, stream>>>(ei, ea, et, cursor, rec, E);
    k_wpack<<<160, 64, 0, stream>>>(W1, W2, wpk);

    int gblocks = (N + 63)/64;
    // phase 1: layer-1
    for (int g0 = 0; g0 < 8; g0 += G1) {
        int Gc = (8 - g0 < G1) ? (8 - g0) : G1;
        k_zero<<<512, 256, 0, stream>>>((uint4*)Sepool, (size_t)Gc*halfBytes/16);
        k_vgemm<<<gblocks, 256, 0, stream>>>(nbuf, wpk, 0, g0, Gc, Vpool, planeElems, N);
        k_edge1s<<<nwin, 256, 0, stream>>>(rec, Vpool, Sepool, acc1, We, be,
                                           g0, Gc, planeElems, halfElems);
        k_segemm<<<gblocks, 256, 0, stream>>>(Sepool, wpk, g0, Gc, acc1, halfElems, N);
    }
    k_hrow<<<N, 64, 0, stream>>>(acc1, acc2, Wroot2, b2);
    // phase 2: layer-2
    for (int g0 = 0; g0 < 8; g0 += G2) {
        int Gc = (8 - g0 < G2) ? (8 - g0) : G2;
        k_zero<<<512, 256, 0, stream>>>((uint4*)Mrpool, (size_t)Gc*planeBytes/16);
        k_vgemm<<<gblocks, 256, 0, stream>>>(acc1, wpk, 16, g0, Gc, Upool, planeElems, N);
        k_edge2s<<<nwin, 256, 0, stream>>>(rec, Upool, Mrpool, g0, Gc, planeElems);
        k_merge<<<1024, 256, 0, stream>>>(Mrpool, acc2, planeElems, planeElems, Gc);
    }
    k_final<<<N, 64, 0, stream>>>(acc2, omega, Wo, bo, Wagg, bagg, Wc, bc, out);
}

// Round 7
// 1523.324 us; speedup vs baseline: 2.3615x; 1.0479x over previous
//
#include <hip/hip_runtime.h>
#include <cmath>

typedef __attribute__((ext_vector_type(8))) short short8;
typedef __attribute__((ext_vector_type(4))) float floatx4;

// ---------- helpers ----------
__device__ __forceinline__ unsigned encf(float f) {
    unsigned u = __float_as_uint(f);
    return (u & 0x80000000u) ? ~u : (u | 0x80000000u);
}
__device__ __forceinline__ float decf(unsigned v) {
    unsigned u = (v & 0x80000000u) ? (v ^ 0x80000000u) : ~v;
    return __uint_as_float(u);
}
// round-to-nearest-even fp32 -> bf16 bits
__device__ __forceinline__ unsigned short rnbf(float f) {
    unsigned u = __float_as_uint(f);
    u += 0x7fffu + ((u >> 16) & 1u);
    return (unsigned short)(u >> 16);
}
__device__ __forceinline__ float bf2f(unsigned short h) {
    return __uint_as_float(((unsigned)h) << 16);
}

// ---------- K0: encoder. one wave per node ----------
__global__ __launch_bounds__(64) void k_encoder(
    const float* __restrict__ x,
    const float* __restrict__ Wn, const float* __restrict__ bn,
    const float* __restrict__ Wroot1, const float* __restrict__ b1,
    float* __restrict__ nbuf, float* __restrict__ acc1)
{
    int i = blockIdx.x;
    int j = threadIdx.x;
    __shared__ __align__(16) float nS[64];
    float x0 = x[3*i], x1 = x[3*i+1], x2 = x[3*i+2];
    float nj = fmaxf(fmaf(x2, Wn[128+j], fmaf(x1, Wn[64+j], fmaf(x0, Wn[j], bn[j]))), 0.f);
    size_t o64 = (size_t)i*64 + j;
    nbuf[o64] = nj;
    nS[j] = nj;
    __syncthreads();
    float acc = b1[j];
    const float4* n4 = (const float4*)nS;
    #pragma unroll
    for (int c = 0; c < 16; ++c) {
        float4 f = n4[c];
        acc = fmaf(f.x, Wroot1[(4*c+0)*64+j], acc);
        acc = fmaf(f.y, Wroot1[(4*c+1)*64+j], acc);
        acc = fmaf(f.z, Wroot1[(4*c+2)*64+j], acc);
        acc = fmaf(f.w, Wroot1[(4*c+3)*64+j], acc);
    }
    acc1[o64] = acc;
}

// ---------- zero a region (uint4 granularity) ----------
__global__ void k_zero(uint4* __restrict__ dst, size_t n16)
{
    size_t gid = (size_t)blockIdx.x*blockDim.x + threadIdx.x;
    size_t stride = (size_t)gridDim.x*blockDim.x;
    for (size_t k = gid; k < n16; k += stride) dst[k] = make_uint4(0,0,0,0);
}

// ---------- bucket edges by relation ----------
__global__ void k_hist(const int* __restrict__ et, int* __restrict__ cnt, int E)
{
    __shared__ int h[8];
    if (threadIdx.x < 8) h[threadIdx.x] = 0;
    __syncthreads();
    int gid = blockIdx.x*blockDim.x + threadIdx.x;
    int stride = gridDim.x*blockDim.x;
    for (int e = gid; e < E; e += stride) atomicAdd(&h[et[e]], 1);
    __syncthreads();
    if (threadIdx.x < 8) atomicAdd(&cnt[threadIdx.x], h[threadIdx.x]);
}

__global__ void k_scan(const int* __restrict__ cnt, int* __restrict__ cursor, int EPB)
{
    if (threadIdx.x == 0) {
        int o = 0;
        for (int r = 0; r < 8; ++r) {
            cursor[r] = o;
            int c = cnt[r];
            o += ((c + EPB - 1)/EPB)*EPB;
        }
    }
}

__global__ void k_scatter(const int* __restrict__ ei, const float* __restrict__ ea,
                          const int* __restrict__ et, int* __restrict__ cursor,
                          int4* __restrict__ rec, int E)
{
    __shared__ int h[8];
    __shared__ int base8[8];
    if (threadIdx.x < 8) h[threadIdx.x] = 0;
    __syncthreads();
    int e = blockIdx.x*blockDim.x + threadIdx.x;
    int r = 0, lpos = 0;
    bool act = (e < E);
    if (act) { r = et[e]; lpos = atomicAdd(&h[r], 1); }
    __syncthreads();
    if (threadIdx.x < 8)
        base8[threadIdx.x] = (h[threadIdx.x] > 0) ? atomicAdd(&cursor[threadIdx.x], h[threadIdx.x]) : 0;
    __syncthreads();
    if (act) {
        int4 v = make_int4(ei[e], ei[E + e] | (r << 27),
                           __float_as_int(ea[2*e]), __float_as_int(ea[2*e + 1]));
        rec[base8[r] + lpos] = v;
    }
}

// ---------- fill ONLY padding slots with -1 (replaces full rec init) ----------
__global__ void k_padfill(const int* __restrict__ cnt, int4* __restrict__ rec,
                          int nslots, int EPB)
{
    __shared__ int s_end[8], p_end[8];
    if (threadIdx.x == 0) {
        int o = 0;
        for (int r = 0; r < 8; ++r) {
            int c = cnt[r];
            s_end[r] = o + c;
            o += ((c + EPB - 1)/EPB)*EPB;
            p_end[r] = o;
        }
    }
    __syncthreads();
    int4 neg = make_int4(-1,-1,-1,-1);
    for (int r = 0; r < 8; ++r)
        for (int k = s_end[r] + (int)threadIdx.x; k < p_end[r]; k += 256)
            rec[k] = neg;
    int tot = p_end[7];
    for (int k = tot + (int)threadIdx.x; k < nslots; k += 256)
        rec[k] = neg;
}

// ---------- pack weights into MFMA B-fragment order, split bf16 hi/lo ----------
// units: [0,16)=W1A rel=u>>1,ks=u&1 rows0..63; [16,32)=W2; [32,40)=W1B rows64..95
__global__ __launch_bounds__(64) void k_wpack(
    const float* __restrict__ W1, const float* __restrict__ W2,
    unsigned short* __restrict__ wpk)
{
    int unit = blockIdx.x >> 2;
    int jt = blockIdx.x & 3;
    int lane = threadIdx.x;
    const float* Wb;
    int kbase;
    if (unit < 16) {
        Wb = W1 + (size_t)(unit >> 1)*96*64;
        kbase = (unit & 1)*32;
    } else if (unit < 32) {
        Wb = W2 + (size_t)((unit - 16) >> 1)*64*64;
        kbase = ((unit - 16) & 1)*32;
    } else {
        Wb = W1 + (size_t)(unit - 32)*96*64;
        kbase = 64;
    }
    int j = jt*16 + (lane & 15);
    size_t base = (((size_t)unit*4 + jt)*64 + lane)*16;
    #pragma unroll
    for (int i = 0; i < 8; ++i) {
        int k = kbase + (lane >> 4)*8 + i;
        float f = Wb[(size_t)k*64 + j];
        unsigned short hi = rnbf(f);
        unsigned short lo = rnbf(f - bf2f(hi));
        wpk[base + i] = hi;
        wpk[base + 8 + i] = lo;
    }
}

// ---------- dense GEMM via MFMA split-bf16: out_p[n][j] = sum_k F[n][k]*W[rel][k][j] ----------
__global__ __launch_bounds__(256) void k_vgemm(
    const float* __restrict__ F, const unsigned short* __restrict__ wpk,
    int unitBase, int g0, int Gc, float* __restrict__ Vpool,
    size_t plane, int N)
{
    int lane = threadIdx.x & 63;
    int wave = threadIdx.x >> 6;
    int n0 = blockIdx.x*64 + 16*wave;
    int m = lane & 15, q = lane >> 4;
    int node = n0 + m;
    if (node >= N) node = N - 1;
    const float4* Fr = (const float4*)(F + (size_t)node*64);
    short8 ah[2], al[2];
    #pragma unroll
    for (int ks = 0; ks < 2; ++ks) {
        float4 u0 = Fr[ks*8 + q*2];
        float4 u1 = Fr[ks*8 + q*2 + 1];
        float fv[8] = {u0.x,u0.y,u0.z,u0.w,u1.x,u1.y,u1.z,u1.w};
        #pragma unroll
        for (int i = 0; i < 8; ++i) {
            unsigned short hb = rnbf(fv[i]);
            ah[ks][i] = (short)hb;
            al[ks][i] = (short)rnbf(fv[i] - bf2f(hb));
        }
    }
    for (int p = 0; p < Gc; ++p) {
        int rel = g0 + p;
        floatx4 acc[4];
        #pragma unroll
        for (int jt = 0; jt < 4; ++jt) acc[jt] = (floatx4){0.f,0.f,0.f,0.f};
        #pragma unroll
        for (int ks = 0; ks < 2; ++ks) {
            int unit = unitBase + rel*2 + ks;
            #pragma unroll
            for (int jt = 0; jt < 4; ++jt) {
                const unsigned short* qp = wpk + (((size_t)unit*4 + jt)*64 + lane)*16;
                short8 bh = *(const short8*)qp;
                short8 bl = *(const short8*)(qp + 8);
                acc[jt] = __builtin_amdgcn_mfma_f32_16x16x32_bf16(ah[ks], bh, acc[jt], 0,0,0);
                acc[jt] = __builtin_amdgcn_mfma_f32_16x16x32_bf16(ah[ks], bl, acc[jt], 0,0,0);
                acc[jt] = __builtin_amdgcn_mfma_f32_16x16x32_bf16(al[ks], bh, acc[jt], 0,0,0);
            }
        }
        float* Vp = Vpool + (size_t)p*plane;
        #pragma unroll
        for (int jt = 0; jt < 4; ++jt) {
            #pragma unroll
            for (int t = 0; t < 4; ++t) {
                int row = n0 + q*4 + t;
                if (row < N) Vp[(size_t)row*64 + jt*16 + m] = acc[jt][t];
            }
        }
    }
}

// ---------- Se GEMM via MFMA: acc1[n][j] += sum_m Se_p[n][m]*W1B[rel][m][j], K=32 ----------
__global__ __launch_bounds__(256) void k_segemm(
    const float* __restrict__ Sepool, const unsigned short* __restrict__ wpk,
    int g0, int Gc, float* __restrict__ acc1, size_t half, int N)
{
    int lane = threadIdx.x & 63;
    int wave = threadIdx.x >> 6;
    int n0 = blockIdx.x*64 + 16*wave;
    int m = lane & 15, q = lane >> 4;
    int node = n0 + m;
    if (node >= N) node = N - 1;
    for (int p = 0; p < Gc; ++p) {
        int rel = g0 + p;
        const float4* Fr = (const float4*)(Sepool + (size_t)p*half + (size_t)node*32);
        float4 u0 = Fr[q*2];
        float4 u1 = Fr[q*2 + 1];
        float fv[8] = {u0.x,u0.y,u0.z,u0.w,u1.x,u1.y,u1.z,u1.w};
        short8 ah, al;
        #pragma unroll
        for (int i = 0; i < 8; ++i) {
            unsigned short hb = rnbf(fv[i]);
            ah[i] = (short)hb;
            al[i] = (short)rnbf(fv[i] - bf2f(hb));
        }
        floatx4 acc[4];
        #pragma unroll
        for (int jt = 0; jt < 4; ++jt) acc[jt] = (floatx4){0.f,0.f,0.f,0.f};
        int unit = 32 + rel;
        #pragma unroll
        for (int jt = 0; jt < 4; ++jt) {
            const unsigned short* qp = wpk + (((size_t)unit*4 + jt)*64 + lane)*16;
            short8 bh = *(const short8*)qp;
            short8 bl = *(const short8*)(qp + 8);
            acc[jt] = __builtin_amdgcn_mfma_f32_16x16x32_bf16(ah, bh, acc[jt], 0,0,0);
            acc[jt] = __builtin_amdgcn_mfma_f32_16x16x32_bf16(ah, bl, acc[jt], 0,0,0);
            acc[jt] = __builtin_amdgcn_mfma_f32_16x16x32_bf16(al, bh, acc[jt], 0,0,0);
        }
        #pragma unroll
        for (int jt = 0; jt < 4; ++jt) {
            #pragma unroll
            for (int t = 0; t < 4; ++t) {
                int row = n0 + q*4 + t;
                if (row < N) acc1[(size_t)row*64 + jt*16 + m] += acc[jt][t];
            }
        }
    }
}

// ---------- layer-1 edge pass: streaming, 8-way MLP batches ----------
__global__ __launch_bounds__(256) void k_edge1s(
    const int4* __restrict__ rec, const float* __restrict__ Vpool,
    float* __restrict__ Sepool, float* __restrict__ acc1,
    const float* __restrict__ We, const float* __restrict__ be,
    int g0, int Gc, size_t plane, size_t half)
{
    long blk = (long)blockIdx.x * 256;
    int4 h0 = rec[blk];
    if (h0.x < 0) return;
    int rel = __builtin_amdgcn_readfirstlane(h0.y >> 27);
    int p = rel - g0;
    if (p < 0 || p >= Gc) return;
    const float* Vp = Vpool + (size_t)p*plane;
    float* Sep = Sepool + (size_t)p*half;
    int lane = threadIdx.x & 63;
    int wv = __builtin_amdgcn_readfirstlane(threadIdx.x >> 6);
    int4 my = rec[blk + wv*64 + lane];
    unsigned long long bal = __ballot(my.x >= 0);
    int nval = __popcll(bal);
    float we0 = We[lane & 31], we1 = We[32 + (lane & 31)], bev = be[lane & 31];
    int half_sel = lane >> 5;                         // 0 for lanes<32, 1 else
    int i = 0;
    for (; i + 8 <= nval; i += 8) {
        float v[8]; int dv[8]; float ev[8];
        #pragma unroll
        for (int u = 0; u < 8; ++u) {
            int src = __shfl(my.x, i+u);
            dv[u] = __shfl(my.y, i+u) & 0x07FFFFFF;
            float a0 = __int_as_float(__shfl(my.z, i+u));
            float a1 = __int_as_float(__shfl(my.w, i+u));
            ev[u] = fmaxf(fmaf(a1, we1, fmaf(a0, we0, bev)), 0.f);
            v[u] = Vp[(size_t)src*64 + lane];         // 8 independent gathers in flight
        }
        #pragma unroll
        for (int u = 0; u < 8; ++u)
            atomicAdd(acc1 + (size_t)dv[u]*64 + lane, v[u]);
        #pragma unroll
        for (int u = 0; u < 4; ++u) {                 // 2 edges per op, all 64 lanes
            float evp = half_sel ? ev[2*u+1] : ev[2*u];
            int   dvp = half_sel ? dv[2*u+1] : dv[2*u];
            atomicAdd(Sep + (size_t)dvp*32 + (lane & 31), evp);
        }
    }
    for (; i < nval; ++i) {
        int src = __shfl(my.x, i);
        int dv  = __shfl(my.y, i) & 0x07FFFFFF;
        float a0 = __int_as_float(__shfl(my.z, i));
        float a1 = __int_as_float(__shfl(my.w, i));
        float ev = fmaxf(fmaf(a1, we1, fmaf(a0, we0, bev)), 0.f);
        float v = Vp[(size_t)src*64 + lane];
        atomicAdd(acc1 + (size_t)dv*64 + lane, v);
        if (lane < 32) atomicAdd(Sep + (size_t)dv*32 + lane, ev);
    }
}

// ---------- fused relu + root2: acc1->h in place; acc2 = h@Wroot2+b2 ----------
__global__ __launch_bounds__(64) void k_hrow(
    float* __restrict__ acc1, float* __restrict__ acc2,
    const float* __restrict__ Wroot2, const float* __restrict__ b2)
{
    int i = blockIdx.x, j = threadIdx.x;
    __shared__ __align__(16) float hS[64];
    size_t o64 = (size_t)i*64 + j;
    float h = fmaxf(acc1[o64], 0.f);
    acc1[o64] = h;
    hS[j] = h;
    __syncthreads();
    float acc = b2[j];
    const float4* h4 = (const float4*)hS;
    #pragma unroll
    for (int c = 0; c < 16; ++c) {
        float4 f = h4[c];
        acc = fmaf(f.x, Wroot2[(4*c+0)*64+j], acc);
        acc = fmaf(f.y, Wroot2[(4*c+1)*64+j], acc);
        acc = fmaf(f.z, Wroot2[(4*c+2)*64+j], acc);
        acc = fmaf(f.w, Wroot2[(4*c+3)*64+j], acc);
    }
    acc2[o64] = acc;
}

// ---------- layer-2 edge pass: streaming atomicMax, 8-way MLP batches ----------
__global__ __launch_bounds__(256) void k_edge2s(
    const int4* __restrict__ rec, const float* __restrict__ Upool,
    unsigned* __restrict__ Mrpool, int g0, int Gc, size_t plane)
{
    long blk = (long)blockIdx.x * 256;
    int4 h0 = rec[blk];
    if (h0.x < 0) return;
    int rel = __builtin_amdgcn_readfirstlane(h0.y >> 27);
    int p = rel - g0;
    if (p < 0 || p >= Gc) return;
    const float* Up = Upool + (size_t)p*plane;
    unsigned* Mp = Mrpool + (size_t)p*plane;
    int lane = threadIdx.x & 63;
    int wv = __builtin_amdgcn_readfirstlane(threadIdx.x >> 6);
    int4 my = rec[blk + wv*64 + lane];
    unsigned long long bal = __ballot(my.x >= 0);
    int nval = __popcll(bal);
    int i = 0;
    for (; i + 8 <= nval; i += 8) {
        float v[8]; int dv[8];
        #pragma unroll
        for (int u = 0; u < 8; ++u) {
            int src = __shfl(my.x, i+u);
            dv[u] = __shfl(my.y, i+u) & 0x07FFFFFF;
            v[u] = Up[(size_t)src*64 + lane];
        }
        #pragma unroll
        for (int u = 0; u < 8; ++u)
            atomicMax(Mp + (size_t)dv[u]*64 + lane, encf(v[u]));
    }
    for (; i < nval; ++i) {
        int src = __shfl(my.x, i);
        int dv  = __shfl(my.y, i) & 0x07FFFFFF;
        float v = Up[(size_t)src*64 + lane];
        atomicMax(Mp + (size_t)dv*64 + lane, encf(v));
    }
}

// ---------- merge (fallback when relation groups split): acc2 += decode(Mr planes) ----------
__global__ void k_merge(const unsigned* __restrict__ Mr, float* __restrict__ acc2,
                        size_t n, size_t plane, int Gc)
{
    size_t gid = (size_t)blockIdx.x*blockDim.x + threadIdx.x;
    size_t stride = (size_t)gridDim.x*blockDim.x;
    for (size_t k = gid; k < n; k += stride) {
        float s = 0.f;
        for (int g = 0; g < Gc; ++g) {
            unsigned v = Mr[(size_t)g*plane + k];
            if (v) s += decf(v);
        }
        acc2[k] += s;
    }
}

// ---------- head (optionally fused with max-merge over Gfin planes) ----------
__global__ __launch_bounds__(64) void k_final(
    const float* __restrict__ acc2, const unsigned* __restrict__ Mr,
    int Gfin, size_t plane,
    const float* __restrict__ omega,
    const float* __restrict__ Wo, const float* __restrict__ bo,
    const float* __restrict__ Wagg, const float* __restrict__ bagg,
    const float* __restrict__ Wc, const float* __restrict__ bc,
    float* __restrict__ out)
{
    int i = blockIdx.x, j = threadIdx.x;
    __shared__ __align__(16) float cS[128];
    float om0 = omega[2*i], om1 = omega[2*i+1];
    float oj = fmaxf(fmaf(om1, Wo[64+j], fmaf(om0, Wo[j], bo[j])), 0.f);
    float a2 = acc2[(size_t)i*64 + j];
    for (int g = 0; g < Gfin; ++g) {
        unsigned v = Mr[(size_t)g*plane + (size_t)i*64 + j];
        if (v) a2 += decf(v);
    }
    float h2 = fmaxf(a2, 0.f);
    cS[j] = h2;
    cS[64 + j] = oj;
    __syncthreads();
    float t = bagg[j];
    const float4* c4 = (const float4*)cS;
    #pragma unroll
    for (int c = 0; c < 32; ++c) {
        float4 f = c4[c];
        t = fmaf(f.x, Wagg[(4*c+0)*64+j], t);
        t = fmaf(f.y, Wagg[(4*c+1)*64+j], t);
        t = fmaf(f.z, Wagg[(4*c+2)*64+j], t);
        t = fmaf(f.w, Wagg[(4*c+3)*64+j], t);
    }
    t = fmaxf(t, 0.f);
    float part = t * Wc[j];
    #pragma unroll
    for (int off = 32; off; off >>= 1) part += __shfl_xor(part, off);
    if (j == 0) out[i] = tanhf(part + bc[0]) * 5.0f;
}

extern "C" void kernel_launch(void* const* d_in, const int* in_sizes, int n_in,
                              void* d_out, int out_size, void* d_ws, size_t ws_size,
                              hipStream_t stream)
{
    const float* x      = (const float*)d_in[0];
    const int*   ei     = (const int*)d_in[1];
    const float* ea     = (const float*)d_in[2];
    const int*   et     = (const int*)d_in[3];
    const float* omega  = (const float*)d_in[4];
    const float* Wn     = (const float*)d_in[5];
    const float* bn     = (const float*)d_in[6];
    const float* We     = (const float*)d_in[7];
    const float* be     = (const float*)d_in[8];
    const float* Wo     = (const float*)d_in[9];
    const float* bo     = (const float*)d_in[10];
    const float* W1     = (const float*)d_in[11];
    const float* Wroot1 = (const float*)d_in[12];
    const float* b1     = (const float*)d_in[13];
    const float* W2     = (const float*)d_in[14];
    const float* Wroot2 = (const float*)d_in[15];
    const float* b2     = (const float*)d_in[16];
    const float* Wagg   = (const float*)d_in[17];
    const float* bagg   = (const float*)d_in[18];
    const float* Wc     = (const float*)d_in[19];
    const float* bc     = (const float*)d_in[20];
    int N = in_sizes[0] / 3;
    int E = in_sizes[3];
    float* out = (float*)d_out;

    // ---- workspace layout ----
    int nwin   = (E + 255)/256 + 8;
    int nslots = nwin * 256;
    char* pp = (char*)d_ws;
    float* nbuf = (float*)pp;  pp += (size_t)N*64*4;       // n; reused as acc2
    float* acc1 = (float*)pp;  pp += (size_t)N*64*4;       // acc1 -> h
    int4*  rec  = (int4*)pp;   pp += (size_t)nslots*16;
    int*   cnt  = (int*)pp;    pp += 8*4;
    int*   cursor = (int*)pp;  pp += 8*4;
    unsigned short* wpk = (unsigned short*)pp; pp += (size_t)40*4*64*16*2;  // 320KB
    size_t off = (size_t)(pp - (char*)d_ws);
    off = (off + 255) & ~(size_t)255;
    size_t planeElems = (size_t)N*64;
    size_t planeBytes = planeElems*4;
    size_t halfElems  = (size_t)N*32;
    size_t halfBytes  = halfElems*4;
    size_t avail = (ws_size > off) ? (ws_size - off) : 0;
    int G1 = (int)(avail / (planeBytes + halfBytes));
    int G2 = (int)(avail / (2*planeBytes));
    if (G1 > 8) G1 = 8; if (G1 < 1) G1 = 1;
    if (G2 > 8) G2 = 8; if (G2 < 1) G2 = 1;
    float*    poolF = (float*)((char*)d_ws + off);
    float*    Vpool = poolF;
    float*    Sepool = poolF + (size_t)G1*planeElems;
    float*    Upool = poolF;
    unsigned* Mrpool = (unsigned*)(poolF + (size_t)G2*planeElems);
    float* acc2 = nbuf;

    k_encoder<<<N, 64, 0, stream>>>(x, Wn, bn, Wroot1, b1, nbuf, acc1);
    hipMemsetAsync(cnt, 0, 8*sizeof(int), stream);
    k_hist<<<1024, 256, 0, stream>>>(et, cnt, E);
    k_scan<<<1, 64, 0, stream>>>(cnt, cursor, 256);
    k_scatter<<<(E + 255)/256, 256, 0, stream>>>(ei, ea, et, cursor, rec, E);
    k_padfill<<<1, 256, 0, stream>>>(cnt, rec, nslots, 256);
    k_wpack<<<160, 64, 0, stream>>>(W1, W2, wpk);

    int gblocks = (N + 63)/64;
    // phase 1: layer-1
    for (int g0 = 0; g0 < 8; g0 += G1) {
        int Gc = (8 - g0 < G1) ? (8 - g0) : G1;
        k_zero<<<512, 256, 0, stream>>>((uint4*)Sepool, (size_t)Gc*halfBytes/16);
        k_vgemm<<<gblocks, 256, 0, stream>>>(nbuf, wpk, 0, g0, Gc, Vpool, planeElems, N);
        k_edge1s<<<nwin, 256, 0, stream>>>(rec, Vpool, Sepool, acc1, We, be,
                                           g0, Gc, planeElems, halfElems);
        k_segemm<<<gblocks, 256, 0, stream>>>(Sepool, wpk, g0, Gc, acc1, halfElems, N);
    }
    k_hrow<<<N, 64, 0, stream>>>(acc1, acc2, Wroot2, b2);
    // phase 2: layer-2
    int fuseMerge = (G2 >= 8) ? 1 : 0;
    for (int g0 = 0; g0 < 8; g0 += G2) {
        int Gc = (8 - g0 < G2) ? (8 - g0) : G2;
        k_zero<<<512, 256, 0, stream>>>((uint4*)Mrpool, (size_t)Gc*planeBytes/16);
        k_vgemm<<<gblocks, 256, 0, stream>>>(acc1, wpk, 16, g0, Gc, Upool, planeElems, N);
        k_edge2s<<<nwin, 256, 0, stream>>>(rec, Upool, Mrpool, g0, Gc, planeElems);
        if (!fuseMerge)
            k_merge<<<1024, 256, 0, stream>>>(Mrpool, acc2, planeElems, planeElems, Gc);
    }
    k_final<<<N, 64, 0, stream>>>(acc2, Mrpool, fuseMerge ? 8 : 0, planeElems,
                                  omega, Wo, bo, Wagg, bagg, Wc, bc, out);
}

// Round 10
// 1067.146 us; speedup vs baseline: 3.3709x; 1.4275x over previous
//
#include <hip/hip_runtime.h>
#include <cmath>

typedef __attribute__((ext_vector_type(8))) short short8;
typedef __attribute__((ext_vector_type(4))) float floatx4;

// ---------- helpers ----------
__device__ __forceinline__ unsigned short rnbf(float f) {
    unsigned u = __float_as_uint(f);
    u += 0x7fffu + ((u >> 16) & 1u);
    return (unsigned short)(u >> 16);
}
__device__ __forceinline__ float bf2f(unsigned short h) {
    return __uint_as_float(((unsigned)h) << 16);
}

// ---------- K0: encoder. one wave per node ----------
__global__ __launch_bounds__(64) void k_encoder(
    const float* __restrict__ x,
    const float* __restrict__ Wn, const float* __restrict__ bn,
    const float* __restrict__ Wroot1, const float* __restrict__ b1,
    float* __restrict__ nbuf, float* __restrict__ acc1)
{
    int i = blockIdx.x;
    int j = threadIdx.x;
    __shared__ __align__(16) float nS[64];
    float x0 = x[3*i], x1 = x[3*i+1], x2 = x[3*i+2];
    float nj = fmaxf(fmaf(x2, Wn[128+j], fmaf(x1, Wn[64+j], fmaf(x0, Wn[j], bn[j]))), 0.f);
    size_t o64 = (size_t)i*64 + j;
    nbuf[o64] = nj;
    nS[j] = nj;
    __syncthreads();
    float acc = b1[j];
    const float4* n4 = (const float4*)nS;
    #pragma unroll
    for (int c = 0; c < 16; ++c) {
        float4 f = n4[c];
        acc = fmaf(f.x, Wroot1[(4*c+0)*64+j], acc);
        acc = fmaf(f.y, Wroot1[(4*c+1)*64+j], acc);
        acc = fmaf(f.z, Wroot1[(4*c+2)*64+j], acc);
        acc = fmaf(f.w, Wroot1[(4*c+3)*64+j], acc);
    }
    acc1[o64] = acc;
}

// ---------- dst-degree histogram ----------
__global__ void k_histd(const int* __restrict__ ei, int* __restrict__ deg, int E)
{
    int e = blockIdx.x*blockDim.x + threadIdx.x;
    if (e < E) atomicAdd(&deg[ei[E + e]], 1);
}

// ---------- counting-sort scan (3 kernels) ----------
#define SCHUNK 1024
__global__ void k_bsum(const int* __restrict__ deg, int* __restrict__ bsum, int N)
{
    __shared__ int s[256];
    int b = blockIdx.x, t = threadIdx.x;
    int base = b*SCHUNK;
    int v = 0;
    for (int k = t; k < SCHUNK; k += 256) { int i = base + k; v += (i < N) ? deg[i] : 0; }
    s[t] = v; __syncthreads();
    for (int o = 128; o; o >>= 1) { if (t < o) s[t] += s[t+o]; __syncthreads(); }
    if (t == 0) bsum[b] = s[0];
}
__global__ void k_bscan(int* __restrict__ bsum, int nb)
{
    if (threadIdx.x == 0) {
        int acc = 0;
        for (int i = 0; i < nb; ++i) { int v = bsum[i]; bsum[i] = acc; acc += v; }
    }
}
__global__ void k_bapply(const int* __restrict__ deg, const int* __restrict__ bsum,
                         int* __restrict__ off, int* __restrict__ cursor, int N)
{
    __shared__ int ts[256];
    int b = blockIdx.x, t = threadIdx.x;
    int base = b*SCHUNK;
    int v[4]; int loc = 0;
    #pragma unroll
    for (int u = 0; u < 4; ++u) { int i = base + t*4 + u; v[u] = (i < N) ? deg[i] : 0; loc += v[u]; }
    ts[t] = loc; __syncthreads();
    for (int o = 1; o < 256; o <<= 1) {
        int add = (t >= o) ? ts[t-o] : 0;
        __syncthreads();
        ts[t] += add;
        __syncthreads();
    }
    int excl = ts[t] - loc + bsum[b];
    #pragma unroll
    for (int u = 0; u < 4; ++u) {
        int i = base + t*4 + u;
        if (i < N) { off[i] = excl; cursor[i] = excl; }
        excl += v[u];
        if (i == N-1) off[N] = excl;
    }
}

// ---------- scatter edges into dst-sorted order, packed int2 ----------
// x = src | rel<<24 ; y = bf16(a0)<<16 | bf16(a1)
__global__ void k_scatd(const int* __restrict__ ei, const float* __restrict__ ea,
                        const int* __restrict__ et, int* __restrict__ cursor,
                        int2* __restrict__ srec, int E)
{
    int e = blockIdx.x*blockDim.x + threadIdx.x;
    if (e >= E) return;
    int dst = ei[E + e];
    int pos = atomicAdd(&cursor[dst], 1);
    int xv = ei[e] | (et[e] << 24);
    int yv = ((int)rnbf(ea[2*e]) << 16) | (int)rnbf(ea[2*e + 1]);
    srec[pos] = make_int2(xv, yv);
}

// ---------- pack W1A/W2 into MFMA B-fragment order, split bf16 hi/lo ----------
// units: [0,16)=W1A rel=u>>1,ks=u&1 rows0..63 of W1; [16,32)=W2 same
__global__ __launch_bounds__(64) void k_wpack(
    const float* __restrict__ W1, const float* __restrict__ W2,
    unsigned short* __restrict__ wpk)
{
    int unit = blockIdx.x >> 2;
    int jt = blockIdx.x & 3;
    int lane = threadIdx.x;
    const float* Wb;
    int kbase;
    if (unit < 16) {
        Wb = W1 + (size_t)(unit >> 1)*96*64;
        kbase = (unit & 1)*32;
    } else {
        Wb = W2 + (size_t)((unit - 16) >> 1)*64*64;
        kbase = ((unit - 16) & 1)*32;
    }
    int j = jt*16 + (lane & 15);
    size_t base = (((size_t)unit*4 + jt)*64 + lane)*16;
    #pragma unroll
    for (int i = 0; i < 8; ++i) {
        int k = kbase + (lane >> 4)*8 + i;
        float f = Wb[(size_t)k*64 + j];
        unsigned short hi = rnbf(f);
        unsigned short lo = rnbf(f - bf2f(hi));
        wpk[base + i] = hi;
        wpk[base + 8 + i] = lo;
    }
}

// ---------- dense GEMM via MFMA split-bf16, bf16 output (layer 1 V planes) ----------
__global__ __launch_bounds__(256) void k_vgemmB(
    const float* __restrict__ F, const unsigned short* __restrict__ wpk,
    int g0, int Gc, unsigned short* __restrict__ Vbf, size_t plane, int N)
{
    int lane = threadIdx.x & 63;
    int wave = threadIdx.x >> 6;
    int n0 = blockIdx.x*64 + 16*wave;
    int m = lane & 15, q = lane >> 4;
    int node = n0 + m;
    if (node >= N) node = N - 1;
    const float4* Fr = (const float4*)(F + (size_t)node*64);
    short8 ah[2], al[2];
    #pragma unroll
    for (int ks = 0; ks < 2; ++ks) {
        float4 u0 = Fr[ks*8 + q*2];
        float4 u1 = Fr[ks*8 + q*2 + 1];
        float fv[8] = {u0.x,u0.y,u0.z,u0.w,u1.x,u1.y,u1.z,u1.w};
        #pragma unroll
        for (int i = 0; i < 8; ++i) {
            unsigned short hb = rnbf(fv[i]);
            ah[ks][i] = (short)hb;
            al[ks][i] = (short)rnbf(fv[i] - bf2f(hb));
        }
    }
    for (int p = 0; p < Gc; ++p) {
        int rel = g0 + p;
        floatx4 acc[4];
        #pragma unroll
        for (int jt = 0; jt < 4; ++jt) acc[jt] = (floatx4){0.f,0.f,0.f,0.f};
        #pragma unroll
        for (int ks = 0; ks < 2; ++ks) {
            int unit = rel*2 + ks;
            #pragma unroll
            for (int jt = 0; jt < 4; ++jt) {
                const unsigned short* qp = wpk + (((size_t)unit*4 + jt)*64 + lane)*16;
                short8 bh = *(const short8*)qp;
                short8 bl = *(const short8*)(qp + 8);
                acc[jt] = __builtin_amdgcn_mfma_f32_16x16x32_bf16(ah[ks], bh, acc[jt], 0,0,0);
                acc[jt] = __builtin_amdgcn_mfma_f32_16x16x32_bf16(ah[ks], bl, acc[jt], 0,0,0);
                acc[jt] = __builtin_amdgcn_mfma_f32_16x16x32_bf16(al[ks], bh, acc[jt], 0,0,0);
            }
        }
        unsigned short* Vp = Vbf + (size_t)p*plane;
        #pragma unroll
        for (int jt = 0; jt < 4; ++jt) {
            #pragma unroll
            for (int t = 0; t < 4; ++t) {
                int row = n0 + q*4 + t;
                if (row < N) Vp[(size_t)row*64 + jt*16 + m] = rnbf(acc[jt][t]);
            }
        }
    }
}

// ---------- dense GEMM via MFMA split-bf16, fp32 output (layer 2 U planes) ----------
__global__ __launch_bounds__(256) void k_vgemmF(
    const float* __restrict__ F, const unsigned short* __restrict__ wpk,
    int g0, int Gc, float* __restrict__ Uf, size_t plane, int N)
{
    int lane = threadIdx.x & 63;
    int wave = threadIdx.x >> 6;
    int n0 = blockIdx.x*64 + 16*wave;
    int m = lane & 15, q = lane >> 4;
    int node = n0 + m;
    if (node >= N) node = N - 1;
    const float4* Fr = (const float4*)(F + (size_t)node*64);
    short8 ah[2], al[2];
    #pragma unroll
    for (int ks = 0; ks < 2; ++ks) {
        float4 u0 = Fr[ks*8 + q*2];
        float4 u1 = Fr[ks*8 + q*2 + 1];
        float fv[8] = {u0.x,u0.y,u0.z,u0.w,u1.x,u1.y,u1.z,u1.w};
        #pragma unroll
        for (int i = 0; i < 8; ++i) {
            unsigned short hb = rnbf(fv[i]);
            ah[ks][i] = (short)hb;
            al[ks][i] = (short)rnbf(fv[i] - bf2f(hb));
        }
    }
    for (int p = 0; p < Gc; ++p) {
        int rel = g0 + p;
        floatx4 acc[4];
        #pragma unroll
        for (int jt = 0; jt < 4; ++jt) acc[jt] = (floatx4){0.f,0.f,0.f,0.f};
        #pragma unroll
        for (int ks = 0; ks < 2; ++ks) {
            int unit = 16 + rel*2 + ks;
            #pragma unroll
            for (int jt = 0; jt < 4; ++jt) {
                const unsigned short* qp = wpk + (((size_t)unit*4 + jt)*64 + lane)*16;
                short8 bh = *(const short8*)qp;
                short8 bl = *(const short8*)(qp + 8);
                acc[jt] = __builtin_amdgcn_mfma_f32_16x16x32_bf16(ah[ks], bh, acc[jt], 0,0,0);
                acc[jt] = __builtin_amdgcn_mfma_f32_16x16x32_bf16(ah[ks], bl, acc[jt], 0,0,0);
                acc[jt] = __builtin_amdgcn_mfma_f32_16x16x32_bf16(al[ks], bh, acc[jt], 0,0,0);
            }
        }
        float* Up = Uf + (size_t)p*plane;
        #pragma unroll
        for (int jt = 0; jt < 4; ++jt) {
            #pragma unroll
            for (int t = 0; t < 4; ++t) {
                int row = n0 + q*4 + t;
                if (row < N) Up[(size_t)row*64 + jt*16 + m] = acc[jt][t];
            }
        }
    }
}

// ---------- layer-1 aggregation, grid-stride, one wave per node, no atomics.
// Gathers bf16 V planes [g0,g0+Gc); doE pass also does e-sums (all rels) + e-GEMV
// against a block-resident bf16 W1B tile in LDS (rows 64..95 of W1).
__global__ __launch_bounds__(256) void k_agg1(
    const int2* __restrict__ srec, const int* __restrict__ off,
    const unsigned short* __restrict__ Vbf, size_t plane,
    const float* __restrict__ W1, const float* __restrict__ We,
    const float* __restrict__ be,
    float* __restrict__ acc1, int N, int g0, int Gc, int doE)
{
    __shared__ unsigned short WB[8*32*64];   // 32 KB bf16 W1B
    __shared__ float seS[4][32];
    int lane = threadIdx.x & 63;
    int wv = threadIdx.x >> 6;
    if (doE) {
        for (int idx = threadIdx.x; idx < 16384; idx += 256) {
            int rel = idx >> 11, rem = idx & 2047;
            WB[idx] = rnbf(W1[(size_t)rel*6144 + 4096 + rem]);
        }
        __syncthreads();
    }
    float we0 = We[lane & 31], we1 = We[32 + (lane & 31)], bev = be[lane & 31];
    int stride = gridDim.x*4;
    for (int node = blockIdx.x*4 + wv; node < N; node += stride) {
        int s = off[node], e = off[node+1];
        float vsum = 0.f;
        float se0=0,se1=0,se2=0,se3=0,se4=0,se5=0,se6=0,se7=0;
        unsigned pres = 0;
        for (int base = s; base < e; base += 64) {
            int m = e - base; if (m > 64) m = 64;
            int2 my = srec[base + ((lane < m) ? lane : 0)];
            int ii = 0;
            for (; ii + 4 <= m; ii += 4) {
                int rx[4], ry[4];
                #pragma unroll
                for (int u = 0; u < 4; ++u) {
                    rx[u] = __shfl(my.x, ii+u);
                    ry[u] = __shfl(my.y, ii+u);
                }
                float vg[4];
                #pragma unroll
                for (int u = 0; u < 4; ++u) {
                    int src = rx[u] & 0xFFFFFF;
                    int p = (int)(((unsigned)rx[u]) >> 24) - g0;
                    vg[u] = (p >= 0 && p < Gc)
                          ? bf2f(Vbf[(size_t)p*plane + (size_t)src*64 + lane]) : 0.f;
                }
                vsum += (vg[0] + vg[1]) + (vg[2] + vg[3]);
                if (doE) {
                    #pragma unroll
                    for (int u = 0; u < 4; ++u) {
                        int rel = (int)(((unsigned)rx[u]) >> 24);
                        float a0 = bf2f((unsigned short)(((unsigned)ry[u]) >> 16));
                        float a1 = bf2f((unsigned short)(ry[u] & 0xFFFF));
                        float ev = fmaxf(fmaf(a1, we1, fmaf(a0, we0, bev)), 0.f);
                        pres |= (1u << rel);
                        switch (rel) {
                            case 0: se0 += ev; break;  case 1: se1 += ev; break;
                            case 2: se2 += ev; break;  case 3: se3 += ev; break;
                            case 4: se4 += ev; break;  case 5: se5 += ev; break;
                            case 6: se6 += ev; break;  default: se7 += ev; break;
                        }
                    }
                }
            }
            for (; ii < m; ++ii) {
                int rx = __shfl(my.x, ii);
                int ry = __shfl(my.y, ii);
                int src = rx & 0xFFFFFF;
                int rel = (int)(((unsigned)rx) >> 24);
                int p = rel - g0;
                if (p >= 0 && p < Gc)
                    vsum += bf2f(Vbf[(size_t)p*plane + (size_t)src*64 + lane]);
                if (doE) {
                    float a0 = bf2f((unsigned short)(((unsigned)ry) >> 16));
                    float a1 = bf2f((unsigned short)(ry & 0xFFFF));
                    float ev = fmaxf(fmaf(a1, we1, fmaf(a0, we0, bev)), 0.f);
                    pres |= (1u << rel);
                    switch (rel) {
                        case 0: se0 += ev; break;  case 1: se1 += ev; break;
                        case 2: se2 += ev; break;  case 3: se3 += ev; break;
                        case 4: se4 += ev; break;  case 5: se5 += ev; break;
                        case 6: se6 += ev; break;  default: se7 += ev; break;
                    }
                }
            }
        }
        if (doE) {
            for (int rel = 0; rel < 8; ++rel) {
                if (!(pres & (1u << rel))) continue;       // wave-uniform
                float sev;
                switch (rel) {
                    case 0: sev = se0; break;  case 1: sev = se1; break;
                    case 2: sev = se2; break;  case 3: sev = se3; break;
                    case 4: sev = se4; break;  case 5: sev = se5; break;
                    case 6: sev = se6; break;  default: sev = se7; break;
                }
                if (lane < 32) seS[wv][lane] = sev;        // same-wave LDS, no barrier
                float acc = 0.f;
                #pragma unroll
                for (int mm = 0; mm < 32; ++mm)
                    acc = fmaf(seS[wv][mm], bf2f(WB[rel*2048 + mm*64 + lane]), acc);
                vsum += acc;
            }
        }
        acc1[(size_t)node*64 + lane] += vsum;              // exclusive owner
    }
}

// ---------- fused relu + root2: acc1->h in place; acc2 = h@Wroot2+b2 ----------
__global__ __launch_bounds__(64) void k_hrow(
    float* __restrict__ acc1, float* __restrict__ acc2,
    const float* __restrict__ Wroot2, const float* __restrict__ b2)
{
    int i = blockIdx.x, j = threadIdx.x;
    __shared__ __align__(16) float hS[64];
    size_t o64 = (size_t)i*64 + j;
    float h = fmaxf(acc1[o64], 0.f);
    acc1[o64] = h;
    hS[j] = h;
    __syncthreads();
    float acc = b2[j];
    const float4* h4 = (const float4*)hS;
    #pragma unroll
    for (int c = 0; c < 16; ++c) {
        float4 f = h4[c];
        acc = fmaf(f.x, Wroot2[(4*c+0)*64+j], acc);
        acc = fmaf(f.y, Wroot2[(4*c+1)*64+j], acc);
        acc = fmaf(f.z, Wroot2[(4*c+2)*64+j], acc);
        acc = fmaf(f.w, Wroot2[(4*c+3)*64+j], acc);
    }
    acc2[o64] = acc;
}

// ---------- layer-2 aggregation (rels [g0,g0+Gc)): per-rel max regs, no atomics ----------
__global__ __launch_bounds__(256) void k_agg2(
    const int2* __restrict__ srec, const int* __restrict__ off,
    const float* __restrict__ Uf, size_t plane,
    float* __restrict__ acc2, int N, int g0, int Gc)
{
    int lane = threadIdx.x & 63;
    int wv = threadIdx.x >> 6;
    int stride = gridDim.x*4;
    const float NEG = -__builtin_inff();
    for (int node = blockIdx.x*4 + wv; node < N; node += stride) {
        int s = off[node], e = off[node+1];
        float m0,m1,m2,m3,m4,m5,m6,m7;
        m0=m1=m2=m3=m4=m5=m6=m7 = NEG;
        unsigned pres = 0;
        for (int base = s; base < e; base += 64) {
            int m = e - base; if (m > 64) m = 64;
            int2 my = srec[base + ((lane < m) ? lane : 0)];
            int ii = 0;
            for (; ii + 4 <= m; ii += 4) {
                int rx[4];
                #pragma unroll
                for (int u = 0; u < 4; ++u) rx[u] = __shfl(my.x, ii+u);
                float vg[4]; int pc[4];
                #pragma unroll
                for (int u = 0; u < 4; ++u) {
                    int src = rx[u] & 0xFFFFFF;
                    int p = (int)(((unsigned)rx[u]) >> 24) - g0;
                    bool ok = (p >= 0 && p < Gc);
                    pc[u] = ok ? p : 0;
                    vg[u] = ok ? Uf[(size_t)p*plane + (size_t)src*64 + lane] : NEG;
                    if (ok) pres |= (1u << p);
                }
                #pragma unroll
                for (int u = 0; u < 4; ++u) {
                    switch (pc[u]) {
                        case 0: m0 = fmaxf(m0, vg[u]); break;
                        case 1: m1 = fmaxf(m1, vg[u]); break;
                        case 2: m2 = fmaxf(m2, vg[u]); break;
                        case 3: m3 = fmaxf(m3, vg[u]); break;
                        case 4: m4 = fmaxf(m4, vg[u]); break;
                        case 5: m5 = fmaxf(m5, vg[u]); break;
                        case 6: m6 = fmaxf(m6, vg[u]); break;
                        default: m7 = fmaxf(m7, vg[u]); break;
                    }
                }
            }
            for (; ii < m; ++ii) {
                int rx = __shfl(my.x, ii);
                int src = rx & 0xFFFFFF;
                int p = (int)(((unsigned)rx) >> 24) - g0;
                if (p < 0 || p >= Gc) continue;
                float v = Uf[(size_t)p*plane + (size_t)src*64 + lane];
                pres |= (1u << p);
                switch (p) {
                    case 0: m0 = fmaxf(m0, v); break;  case 1: m1 = fmaxf(m1, v); break;
                    case 2: m2 = fmaxf(m2, v); break;  case 3: m3 = fmaxf(m3, v); break;
                    case 4: m4 = fmaxf(m4, v); break;  case 5: m5 = fmaxf(m5, v); break;
                    case 6: m6 = fmaxf(m6, v); break;  default: m7 = fmaxf(m7, v); break;
                }
            }
        }
        float add = 0.f;
        if (pres & 1u)   add += m0;  if (pres & 2u)   add += m1;
        if (pres & 4u)   add += m2;  if (pres & 8u)   add += m3;
        if (pres & 16u)  add += m4;  if (pres & 32u)  add += m5;
        if (pres & 64u)  add += m6;  if (pres & 128u) add += m7;
        acc2[(size_t)node*64 + lane] += add;
    }
}

// ---------- head ----------
__global__ __launch_bounds__(64) void k_final(
    const float* __restrict__ acc2, const float* __restrict__ omega,
    const float* __restrict__ Wo, const float* __restrict__ bo,
    const float* __restrict__ Wagg, const float* __restrict__ bagg,
    const float* __restrict__ Wc, const float* __restrict__ bc,
    float* __restrict__ out)
{
    int i = blockIdx.x, j = threadIdx.x;
    __shared__ __align__(16) float cS[128];
    float om0 = omega[2*i], om1 = omega[2*i+1];
    float oj = fmaxf(fmaf(om1, Wo[64+j], fmaf(om0, Wo[j], bo[j])), 0.f);
    float h2 = fmaxf(acc2[(size_t)i*64 + j], 0.f);
    cS[j] = h2;
    cS[64 + j] = oj;
    __syncthreads();
    float t = bagg[j];
    const float4* c4 = (const float4*)cS;
    #pragma unroll
    for (int c = 0; c < 32; ++c) {
        float4 f = c4[c];
        t = fmaf(f.x, Wagg[(4*c+0)*64+j], t);
        t = fmaf(f.y, Wagg[(4*c+1)*64+j], t);
        t = fmaf(f.z, Wagg[(4*c+2)*64+j], t);
        t = fmaf(f.w, Wagg[(4*c+3)*64+j], t);
    }
    t = fmaxf(t, 0.f);
    float part = t * Wc[j];
    #pragma unroll
    for (int off = 32; off; off >>= 1) part += __shfl_xor(part, off);
    if (j == 0) out[i] = tanhf(part + bc[0]) * 5.0f;
}

extern "C" void kernel_launch(void* const* d_in, const int* in_sizes, int n_in,
                              void* d_out, int out_size, void* d_ws, size_t ws_size,
                              hipStream_t stream)
{
    const float* x      = (const float*)d_in[0];
    const int*   ei     = (const int*)d_in[1];
    const float* ea     = (const float*)d_in[2];
    const int*   et     = (const int*)d_in[3];
    const float* omega  = (const float*)d_in[4];
    const float* Wn     = (const float*)d_in[5];
    const float* bn     = (const float*)d_in[6];
    const float* We     = (const float*)d_in[7];
    const float* be     = (const float*)d_in[8];
    const float* Wo     = (const float*)d_in[9];
    const float* bo     = (const float*)d_in[10];
    const float* W1     = (const float*)d_in[11];
    const float* Wroot1 = (const float*)d_in[12];
    const float* b1     = (const float*)d_in[13];
    const float* W2     = (const float*)d_in[14];
    const float* Wroot2 = (const float*)d_in[15];
    const float* b2     = (const float*)d_in[16];
    const float* Wagg   = (const float*)d_in[17];
    const float* bagg   = (const float*)d_in[18];
    const float* Wc     = (const float*)d_in[19];
    const float* bc     = (const float*)d_in[20];
    int N = in_sizes[0] / 3;
    int E = in_sizes[3];
    float* out = (float*)d_out;

    int nb = (N + SCHUNK - 1)/SCHUNK;

    // ---- workspace layout: fixed ~65.5 MB + adaptive pool (fits 128 MiB) ----
    char* pp = (char*)d_ws;
    float* nbuf   = (float*)pp;  pp += (size_t)N*64*4;      // n; reused as acc2
    float* acc1   = (float*)pp;  pp += (size_t)N*64*4;      // acc1 -> h
    int2*  srec   = (int2*)pp;   pp += (size_t)E*8;         // dst-sorted packed edges
    int*   deg    = (int*)pp;    pp += (size_t)N*4;
    int*   dstOff = (int*)pp;    pp += (size_t)(N+1)*4;
    int*   cursor = (int*)pp;    pp += (size_t)N*4;
    int*   bsum   = (int*)pp;    pp += (size_t)nb*4;
    unsigned short* wpk = (unsigned short*)pp; pp += (size_t)32*4*64*16*2;  // 256 KB
    size_t off = ((size_t)(pp - (char*)d_ws) + 255) & ~(size_t)255;
    size_t planeElems = (size_t)N*64;
    size_t avail = (ws_size > off) ? (ws_size - off) : 0;
    int G1 = (int)(avail / (planeElems*2));                 // bf16 V planes
    int G2 = (int)(avail / (planeElems*4));                 // fp32 U planes
    if (G1 > 8) G1 = 8; if (G1 < 1) G1 = 1;
    if (G2 > 8) G2 = 8; if (G2 < 1) G2 = 1;
    unsigned short* Vbf = (unsigned short*)((char*)d_ws + off);
    float*          Uf  = (float*)((char*)d_ws + off);
    float* acc2 = nbuf;

    k_encoder<<<N, 64, 0, stream>>>(x, Wn, bn, Wroot1, b1, nbuf, acc1);
    hipMemsetAsync(deg, 0, (size_t)N*4, stream);
    k_histd<<<(E + 255)/256, 256, 0, stream>>>(ei, deg, E);
    k_bsum<<<nb, 256, 0, stream>>>(deg, bsum, N);
    k_bscan<<<1, 64, 0, stream>>>(bsum, nb);
    k_bapply<<<nb, 256, 0, stream>>>(deg, bsum, dstOff, cursor, N);
    k_scatd<<<(E + 255)/256, 256, 0, stream>>>(ei, ea, et, cursor, srec, E);
    k_wpack<<<128, 64, 0, stream>>>(W1, W2, wpk);

    int gblocks = (N + 63)/64;
    int aggBlocks = 4096;
    // layer 1 (bf16 V planes, grouped over relations; e-path on first pass)
    for (int g0 = 0; g0 < 8; g0 += G1) {
        int Gc = (8 - g0 < G1) ? (8 - g0) : G1;
        k_vgemmB<<<gblocks, 256, 0, stream>>>(nbuf, wpk, g0, Gc, Vbf, planeElems, N);
        k_agg1<<<aggBlocks, 256, 0, stream>>>(srec, dstOff, Vbf, planeElems, W1, We, be,
                                              acc1, N, g0, Gc, (g0 == 0) ? 1 : 0);
    }
    k_hrow<<<N, 64, 0, stream>>>(acc1, acc2, Wroot2, b2);
    // layer 2 (fp32 U planes, grouped over relations)
    for (int g0 = 0; g0 < 8; g0 += G2) {
        int Gc = (8 - g0 < G2) ? (8 - g0) : G2;
        k_vgemmF<<<gblocks, 256, 0, stream>>>(acc1, wpk, g0, Gc, Uf, planeElems, N);
        k_agg2<<<aggBlocks, 256, 0, stream>>>(srec, dstOff, Uf, planeElems, acc2, N, g0, Gc);
    }
    k_final<<<N, 64, 0, stream>>>(acc2, omega, Wo, bo, Wagg, bagg, Wc, bc, out);
}

// Round 11
// 898.526 us; speedup vs baseline: 4.0035x; 1.1877x over previous
//
#include <hip/hip_runtime.h>
#include <cmath>

typedef __attribute__((ext_vector_type(8))) short short8;
typedef __attribute__((ext_vector_type(4))) float floatx4;

// ---------- helpers ----------
__device__ __forceinline__ unsigned short rnbf(float f) {
    unsigned u = __float_as_uint(f);
    u += 0x7fffu + ((u >> 16) & 1u);
    return (unsigned short)(u >> 16);
}
__device__ __forceinline__ float bf2f(unsigned short h) {
    return __uint_as_float(((unsigned)h) << 16);
}

// ---------- K0: encoder. one wave per node ----------
__global__ __launch_bounds__(64) void k_encoder(
    const float* __restrict__ x,
    const float* __restrict__ Wn, const float* __restrict__ bn,
    const float* __restrict__ Wroot1, const float* __restrict__ b1,
    float* __restrict__ nbuf, float* __restrict__ acc1)
{
    int i = blockIdx.x;
    int j = threadIdx.x;
    __shared__ __align__(16) float nS[64];
    float x0 = x[3*i], x1 = x[3*i+1], x2 = x[3*i+2];
    float nj = fmaxf(fmaf(x2, Wn[128+j], fmaf(x1, Wn[64+j], fmaf(x0, Wn[j], bn[j]))), 0.f);
    size_t o64 = (size_t)i*64 + j;
    nbuf[o64] = nj;
    nS[j] = nj;
    __syncthreads();
    float acc = b1[j];
    const float4* n4 = (const float4*)nS;
    #pragma unroll
    for (int c = 0; c < 16; ++c) {
        float4 f = n4[c];
        acc = fmaf(f.x, Wroot1[(4*c+0)*64+j], acc);
        acc = fmaf(f.y, Wroot1[(4*c+1)*64+j], acc);
        acc = fmaf(f.z, Wroot1[(4*c+2)*64+j], acc);
        acc = fmaf(f.w, Wroot1[(4*c+3)*64+j], acc);
    }
    acc1[o64] = acc;
}

// ---------- (dst,rel)-key histogram ----------
__global__ void k_histd(const int* __restrict__ ei, const int* __restrict__ et,
                        int* __restrict__ deg8, int E)
{
    int e = blockIdx.x*blockDim.x + threadIdx.x;
    if (e < E) atomicAdd(&deg8[ei[E + e]*8 + et[e]], 1);
}

// ---------- counting-sort scan over K=N*8 keys ----------
#define SCHUNK 1024
__global__ void k_bsum(const int* __restrict__ deg, int* __restrict__ bsum, int K)
{
    __shared__ int s[256];
    int b = blockIdx.x, t = threadIdx.x;
    int base = b*SCHUNK;
    int v = 0;
    for (int k = t; k < SCHUNK; k += 256) { int i = base + k; v += (i < K) ? deg[i] : 0; }
    s[t] = v; __syncthreads();
    for (int o = 128; o; o >>= 1) { if (t < o) s[t] += s[t+o]; __syncthreads(); }
    if (t == 0) bsum[b] = s[0];
}
// single-block parallel exclusive scan over nb (<=1024) block sums
__global__ void k_bscan(int* __restrict__ bsum, int nb)
{
    __shared__ int ts[256];
    int t = threadIdx.x;
    int v[4]; int loc = 0;
    #pragma unroll
    for (int u = 0; u < 4; ++u) { int i = t*4+u; v[u] = (i < nb) ? bsum[i] : 0; loc += v[u]; }
    ts[t] = loc; __syncthreads();
    for (int o = 1; o < 256; o <<= 1) {
        int add = (t >= o) ? ts[t-o] : 0;
        __syncthreads();
        ts[t] += add;
        __syncthreads();
    }
    int excl = ts[t] - loc;
    #pragma unroll
    for (int u = 0; u < 4; ++u) {
        int i = t*4+u;
        if (i < nb) bsum[i] = excl;
        excl += v[u];
    }
}
__global__ void k_bapply(const int* __restrict__ deg, const int* __restrict__ bsum,
                         int* __restrict__ off, int* __restrict__ cursor, int K)
{
    __shared__ int ts[256];
    int b = blockIdx.x, t = threadIdx.x;
    int base = b*SCHUNK;
    int v[4]; int loc = 0;
    #pragma unroll
    for (int u = 0; u < 4; ++u) { int i = base + t*4 + u; v[u] = (i < K) ? deg[i] : 0; loc += v[u]; }
    ts[t] = loc; __syncthreads();
    for (int o = 1; o < 256; o <<= 1) {
        int add = (t >= o) ? ts[t-o] : 0;
        __syncthreads();
        ts[t] += add;
        __syncthreads();
    }
    int excl = ts[t] - loc + bsum[b];
    #pragma unroll
    for (int u = 0; u < 4; ++u) {
        int i = base + t*4 + u;
        if (i < K) { off[i] = excl; cursor[i] = excl; }
        excl += v[u];
        if (i == K-1) off[K] = excl;
    }
}

// ---------- scatter edges into (dst,rel)-sorted order, packed int2 ----------
// x = src | rel<<24 ; y = bf16(a0)<<16 | bf16(a1)
__global__ void k_scatd(const int* __restrict__ ei, const float* __restrict__ ea,
                        const int* __restrict__ et, int* __restrict__ cursor,
                        int2* __restrict__ srec, int E)
{
    int e = blockIdx.x*blockDim.x + threadIdx.x;
    if (e >= E) return;
    int rel = et[e];
    int key = ei[E + e]*8 + rel;
    int pos = atomicAdd(&cursor[key], 1);
    int xv = ei[e] | (rel << 24);
    int yv = ((int)rnbf(ea[2*e]) << 16) | (int)rnbf(ea[2*e + 1]);
    srec[pos] = make_int2(xv, yv);
}

// ---------- pack W1A/W2 into MFMA B-fragment order, split bf16 hi/lo ----------
// units: [0,16)=W1A rel=u>>1,ks=u&1 rows0..63 of W1; [16,32)=W2 same
__global__ __launch_bounds__(64) void k_wpack(
    const float* __restrict__ W1, const float* __restrict__ W2,
    unsigned short* __restrict__ wpk)
{
    int unit = blockIdx.x >> 2;
    int jt = blockIdx.x & 3;
    int lane = threadIdx.x;
    const float* Wb;
    int kbase;
    if (unit < 16) {
        Wb = W1 + (size_t)(unit >> 1)*96*64;
        kbase = (unit & 1)*32;
    } else {
        Wb = W2 + (size_t)((unit - 16) >> 1)*64*64;
        kbase = ((unit - 16) & 1)*32;
    }
    int j = jt*16 + (lane & 15);
    size_t base = (((size_t)unit*4 + jt)*64 + lane)*16;
    #pragma unroll
    for (int i = 0; i < 8; ++i) {
        int k = kbase + (lane >> 4)*8 + i;
        float f = Wb[(size_t)k*64 + j];
        unsigned short hi = rnbf(f);
        unsigned short lo = rnbf(f - bf2f(hi));
        wpk[base + i] = hi;
        wpk[base + 8 + i] = lo;
    }
}

// ---------- dense GEMM via MFMA split-bf16, bf16 output ----------
__global__ __launch_bounds__(256) void k_vgemmB(
    const float* __restrict__ F, const unsigned short* __restrict__ wpk,
    int unitBase, int g0, int Gc, unsigned short* __restrict__ Vbf,
    size_t plane, int N)
{
    int lane = threadIdx.x & 63;
    int wave = threadIdx.x >> 6;
    int n0 = blockIdx.x*64 + 16*wave;
    int m = lane & 15, q = lane >> 4;
    int node = n0 + m;
    if (node >= N) node = N - 1;
    const float4* Fr = (const float4*)(F + (size_t)node*64);
    short8 ah[2], al[2];
    #pragma unroll
    for (int ks = 0; ks < 2; ++ks) {
        float4 u0 = Fr[ks*8 + q*2];
        float4 u1 = Fr[ks*8 + q*2 + 1];
        float fv[8] = {u0.x,u0.y,u0.z,u0.w,u1.x,u1.y,u1.z,u1.w};
        #pragma unroll
        for (int i = 0; i < 8; ++i) {
            unsigned short hb = rnbf(fv[i]);
            ah[ks][i] = (short)hb;
            al[ks][i] = (short)rnbf(fv[i] - bf2f(hb));
        }
    }
    for (int p = 0; p < Gc; ++p) {
        int rel = g0 + p;
        floatx4 acc[4];
        #pragma unroll
        for (int jt = 0; jt < 4; ++jt) acc[jt] = (floatx4){0.f,0.f,0.f,0.f};
        #pragma unroll
        for (int ks = 0; ks < 2; ++ks) {
            int unit = unitBase + rel*2 + ks;
            #pragma unroll
            for (int jt = 0; jt < 4; ++jt) {
                const unsigned short* qp = wpk + (((size_t)unit*4 + jt)*64 + lane)*16;
                short8 bh = *(const short8*)qp;
                short8 bl = *(const short8*)(qp + 8);
                acc[jt] = __builtin_amdgcn_mfma_f32_16x16x32_bf16(ah[ks], bh, acc[jt], 0,0,0);
                acc[jt] = __builtin_amdgcn_mfma_f32_16x16x32_bf16(ah[ks], bl, acc[jt], 0,0,0);
                acc[jt] = __builtin_amdgcn_mfma_f32_16x16x32_bf16(al[ks], bh, acc[jt], 0,0,0);
            }
        }
        unsigned short* Vp = Vbf + (size_t)p*plane;
        #pragma unroll
        for (int jt = 0; jt < 4; ++jt) {
            #pragma unroll
            for (int t = 0; t < 4; ++t) {
                int row = n0 + q*4 + t;
                if (row < N) Vp[(size_t)row*64 + jt*16 + m] = rnbf(acc[jt][t]);
            }
        }
    }
}

// ---------- layer-1 pass 1: V-gather for rels [0,Gc) + e-path for ALL rels.
// (dst,rel)-sorted srec: per-node range is contiguous, rel runs inside.
__global__ __launch_bounds__(256) void k_agg1e(
    const int2* __restrict__ srec, const int* __restrict__ off8,
    const unsigned short* __restrict__ Vbf, size_t plane,
    const float* __restrict__ W1, const float* __restrict__ We,
    const float* __restrict__ be,
    float* __restrict__ acc1, int N, int Gc)
{
    __shared__ unsigned short WB[8*32*64];   // 32 KB bf16 W1B (rows 64..95 of W1)
    __shared__ float seS[4][32];
    int lane = threadIdx.x & 63;
    int wv = threadIdx.x >> 6;
    for (int idx = threadIdx.x; idx < 16384; idx += 256) {
        int rel = idx >> 11, rem = idx & 2047;
        WB[idx] = rnbf(W1[(size_t)rel*6144 + 4096 + rem]);
    }
    __syncthreads();
    float we0 = We[lane & 31], we1 = We[32 + (lane & 31)], bev = be[lane & 31];
    int stride = gridDim.x*4;
    for (int node = blockIdx.x*4 + wv; node < N; node += stride) {
        int s0 = off8[node*8];
        int eG = off8[node*8 + Gc];
        int e8 = off8[node*8 + 8];
        float vsum = 0.f;
        // ---- phase A: batched V-gather over [s0, eG) (all rels < Gc, no filter) ----
        for (int base = s0; base < eG; base += 64) {
            int m = eG - base; if (m > 64) m = 64;
            int2 my = srec[base + ((lane < m) ? lane : m-1)];
            int ii = 0;
            for (; ii + 4 <= m; ii += 4) {
                float vg[4];
                #pragma unroll
                for (int u = 0; u < 4; ++u) {
                    int rx = __shfl(my.x, ii+u);
                    int src = rx & 0xFFFFFF;
                    int p = (int)(((unsigned)rx) >> 24);
                    vg[u] = bf2f(Vbf[(size_t)p*plane + (size_t)src*64 + lane]);
                }
                vsum += (vg[0] + vg[1]) + (vg[2] + vg[3]);
            }
            for (; ii < m; ++ii) {
                int rx = __shfl(my.x, ii);
                int src = rx & 0xFFFFFF;
                int p = (int)(((unsigned)rx) >> 24);
                vsum += bf2f(Vbf[(size_t)p*plane + (size_t)src*64 + lane]);
            }
        }
        // ---- phase B: e-path over [s0, e8), run-flush GEMV on rel change ----
        float evsum = 0.f;
        int curRel = -1;
        for (int base = s0; base < e8; base += 64) {
            int m = e8 - base; if (m > 64) m = 64;
            int2 my = srec[base + ((lane < m) ? lane : m-1)];
            for (int ii = 0; ii < m; ++ii) {
                int rel = __builtin_amdgcn_readfirstlane(__shfl(my.x, ii)) >> 24;
                int ry = __shfl(my.y, ii);
                if (rel != curRel) {
                    if (curRel >= 0) {
                        if (lane < 32) seS[wv][lane] = evsum;
                        float aa = 0.f, ab = 0.f;
                        #pragma unroll
                        for (int mm = 0; mm < 16; ++mm) {
                            aa = fmaf(seS[wv][mm],    bf2f(WB[curRel*2048 + mm*64 + lane]), aa);
                            ab = fmaf(seS[wv][16+mm], bf2f(WB[curRel*2048 + (16+mm)*64 + lane]), ab);
                        }
                        vsum += aa + ab;
                    }
                    curRel = rel;
                    evsum = 0.f;
                }
                float a0 = bf2f((unsigned short)(((unsigned)ry) >> 16));
                float a1 = bf2f((unsigned short)(ry & 0xFFFF));
                evsum += fmaxf(fmaf(a1, we1, fmaf(a0, we0, bev)), 0.f);
            }
        }
        if (curRel >= 0) {
            if (lane < 32) seS[wv][lane] = evsum;
            float aa = 0.f, ab = 0.f;
            #pragma unroll
            for (int mm = 0; mm < 16; ++mm) {
                aa = fmaf(seS[wv][mm],    bf2f(WB[curRel*2048 + mm*64 + lane]), aa);
                ab = fmaf(seS[wv][16+mm], bf2f(WB[curRel*2048 + (16+mm)*64 + lane]), ab);
            }
            vsum += aa + ab;
        }
        acc1[(size_t)node*64 + lane] += vsum;
    }
}

// ---------- layer-1 pass 2+: V-gather only for rels [g0,g1) ----------
__global__ __launch_bounds__(256) void k_agg1v(
    const int2* __restrict__ srec, const int* __restrict__ off8,
    const unsigned short* __restrict__ Vbf, size_t plane,
    float* __restrict__ acc1, int N, int g0, int g1)
{
    int lane = threadIdx.x & 63;
    int wv = threadIdx.x >> 6;
    int stride = gridDim.x*4;
    for (int node = blockIdx.x*4 + wv; node < N; node += stride) {
        int s = off8[node*8 + g0];
        int e = off8[node*8 + g1];
        if (s == e) continue;
        float vsum = 0.f;
        for (int base = s; base < e; base += 64) {
            int m = e - base; if (m > 64) m = 64;
            int2 my = srec[base + ((lane < m) ? lane : m-1)];
            int ii = 0;
            for (; ii + 4 <= m; ii += 4) {
                float vg[4];
                #pragma unroll
                for (int u = 0; u < 4; ++u) {
                    int rx = __shfl(my.x, ii+u);
                    int src = rx & 0xFFFFFF;
                    int p = (int)(((unsigned)rx) >> 24) - g0;
                    vg[u] = bf2f(Vbf[(size_t)p*plane + (size_t)src*64 + lane]);
                }
                vsum += (vg[0] + vg[1]) + (vg[2] + vg[3]);
            }
            for (; ii < m; ++ii) {
                int rx = __shfl(my.x, ii);
                int src = rx & 0xFFFFFF;
                int p = (int)(((unsigned)rx) >> 24) - g0;
                vsum += bf2f(Vbf[(size_t)p*plane + (size_t)src*64 + lane]);
            }
        }
        acc1[(size_t)node*64 + lane] += vsum;
    }
}

// ---------- fused relu + root2: acc1->h in place; acc2 = h@Wroot2+b2 ----------
__global__ __launch_bounds__(64) void k_hrow(
    float* __restrict__ acc1, float* __restrict__ acc2,
    const float* __restrict__ Wroot2, const float* __restrict__ b2)
{
    int i = blockIdx.x, j = threadIdx.x;
    __shared__ __align__(16) float hS[64];
    size_t o64 = (size_t)i*64 + j;
    float h = fmaxf(acc1[o64], 0.f);
    acc1[o64] = h;
    hS[j] = h;
    __syncthreads();
    float acc = b2[j];
    const float4* h4 = (const float4*)hS;
    #pragma unroll
    for (int c = 0; c < 16; ++c) {
        float4 f = h4[c];
        acc = fmaf(f.x, Wroot2[(4*c+0)*64+j], acc);
        acc = fmaf(f.y, Wroot2[(4*c+1)*64+j], acc);
        acc = fmaf(f.z, Wroot2[(4*c+2)*64+j], acc);
        acc = fmaf(f.w, Wroot2[(4*c+3)*64+j], acc);
    }
    acc2[o64] = acc;
}

// ---------- layer-2: per-rel-run max (flush on rel change), rels [g0,g1) ----------
__global__ __launch_bounds__(256) void k_agg2(
    const int2* __restrict__ srec, const int* __restrict__ off8,
    const unsigned short* __restrict__ Ubf, size_t plane,
    float* __restrict__ acc2, int N, int g0, int g1)
{
    int lane = threadIdx.x & 63;
    int wv = threadIdx.x >> 6;
    int stride = gridDim.x*4;
    const float NEG = -__builtin_inff();
    for (int node = blockIdx.x*4 + wv; node < N; node += stride) {
        int s = off8[node*8 + g0];
        int e = off8[node*8 + g1];
        if (s == e) continue;
        float add = 0.f;
        float mx = NEG;
        int curRel = -1;
        for (int base = s; base < e; base += 64) {
            int m = e - base; if (m > 64) m = 64;
            int2 my = srec[base + ((lane < m) ? lane : m-1)];
            int ii = 0;
            for (; ii + 4 <= m; ii += 4) {
                float vg[4]; int rl[4];
                #pragma unroll
                for (int u = 0; u < 4; ++u) {
                    int rx = __shfl(my.x, ii+u);
                    int src = rx & 0xFFFFFF;
                    int p = (int)(((unsigned)rx) >> 24) - g0;
                    rl[u] = p;
                    vg[u] = bf2f(Ubf[(size_t)p*plane + (size_t)src*64 + lane]);
                }
                #pragma unroll
                for (int u = 0; u < 4; ++u) {
                    int r = __builtin_amdgcn_readfirstlane(rl[u]);
                    if (r != curRel) {
                        if (curRel >= 0) add += mx;
                        curRel = r; mx = NEG;
                    }
                    mx = fmaxf(mx, vg[u]);
                }
            }
            for (; ii < m; ++ii) {
                int rx = __shfl(my.x, ii);
                int src = rx & 0xFFFFFF;
                int p = (int)(((unsigned)rx) >> 24) - g0;
                float v = bf2f(Ubf[(size_t)p*plane + (size_t)src*64 + lane]);
                int r = __builtin_amdgcn_readfirstlane(p);
                if (r != curRel) {
                    if (curRel >= 0) add += mx;
                    curRel = r; mx = NEG;
                }
                mx = fmaxf(mx, v);
            }
        }
        if (curRel >= 0) add += mx;
        acc2[(size_t)node*64 + lane] += add;
    }
}

// ---------- head ----------
__global__ __launch_bounds__(64) void k_final(
    const float* __restrict__ acc2, const float* __restrict__ omega,
    const float* __restrict__ Wo, const float* __restrict__ bo,
    const float* __restrict__ Wagg, const float* __restrict__ bagg,
    const float* __restrict__ Wc, const float* __restrict__ bc,
    float* __restrict__ out)
{
    int i = blockIdx.x, j = threadIdx.x;
    __shared__ __align__(16) float cS[128];
    float om0 = omega[2*i], om1 = omega[2*i+1];
    float oj = fmaxf(fmaf(om1, Wo[64+j], fmaf(om0, Wo[j], bo[j])), 0.f);
    float h2 = fmaxf(acc2[(size_t)i*64 + j], 0.f);
    cS[j] = h2;
    cS[64 + j] = oj;
    __syncthreads();
    float t = bagg[j];
    const float4* c4 = (const float4*)cS;
    #pragma unroll
    for (int c = 0; c < 32; ++c) {
        float4 f = c4[c];
        t = fmaf(f.x, Wagg[(4*c+0)*64+j], t);
        t = fmaf(f.y, Wagg[(4*c+1)*64+j], t);
        t = fmaf(f.z, Wagg[(4*c+2)*64+j], t);
        t = fmaf(f.w, Wagg[(4*c+3)*64+j], t);
    }
    t = fmaxf(t, 0.f);
    float part = t * Wc[j];
    #pragma unroll
    for (int off = 32; off; off >>= 1) part += __shfl_xor(part, off);
    if (j == 0) out[i] = tanhf(part + bc[0]) * 5.0f;
}

extern "C" void kernel_launch(void* const* d_in, const int* in_sizes, int n_in,
                              void* d_out, int out_size, void* d_ws, size_t ws_size,
                              hipStream_t stream)
{
    const float* x      = (const float*)d_in[0];
    const int*   ei     = (const int*)d_in[1];
    const float* ea     = (const float*)d_in[2];
    const int*   et     = (const int*)d_in[3];
    const float* omega  = (const float*)d_in[4];
    const float* Wn     = (const float*)d_in[5];
    const float* bn     = (const float*)d_in[6];
    const float* We     = (const float*)d_in[7];
    const float* be     = (const float*)d_in[8];
    const float* Wo     = (const float*)d_in[9];
    const float* bo     = (const float*)d_in[10];
    const float* W1     = (const float*)d_in[11];
    const float* Wroot1 = (const float*)d_in[12];
    const float* b1     = (const float*)d_in[13];
    const float* W2     = (const float*)d_in[14];
    const float* Wroot2 = (const float*)d_in[15];
    const float* b2     = (const float*)d_in[16];
    const float* Wagg   = (const float*)d_in[17];
    const float* bagg   = (const float*)d_in[18];
    const float* Wc     = (const float*)d_in[19];
    const float* bc     = (const float*)d_in[20];
    int N = in_sizes[0] / 3;
    int E = in_sizes[3];
    float* out = (float*)d_out;

    int K8 = N*8;
    int nb = (K8 + SCHUNK - 1)/SCHUNK;

    // ---- workspace layout: fixed ~74 MB + adaptive bf16 plane pool ----
    char* pp = (char*)d_ws;
    float* nbuf   = (float*)pp;  pp += (size_t)N*64*4;      // n; reused as acc2
    float* acc1   = (float*)pp;  pp += (size_t)N*64*4;      // acc1 -> h
    int2*  srec   = (int2*)pp;   pp += (size_t)E*8;         // (dst,rel)-sorted packed edges
    int*   deg8   = (int*)pp;    pp += (size_t)K8*4;
    int*   off8   = (int*)pp;    pp += (size_t)(K8+1)*4;
    int*   cursor = (int*)pp;    pp += (size_t)K8*4;
    int*   bsum   = (int*)pp;    pp += (size_t)nb*4;
    unsigned short* wpk = (unsigned short*)pp; pp += (size_t)32*4*64*16*2;  // 256 KB
    size_t off = ((size_t)(pp - (char*)d_ws) + 255) & ~(size_t)255;
    size_t planeElems = (size_t)N*64;
    size_t avail = (ws_size > off) ? (ws_size - off) : 0;
    int G = (int)(avail / (planeElems*2));                  // bf16 planes
    if (G > 8) G = 8;
    if (G < 1) G = 1;
    unsigned short* Vbf = (unsigned short*)((char*)d_ws + off);
    float* acc2 = nbuf;

    k_encoder<<<N, 64, 0, stream>>>(x, Wn, bn, Wroot1, b1, nbuf, acc1);
    hipMemsetAsync(deg8, 0, (size_t)K8*4, stream);
    k_histd<<<(E + 255)/256, 256, 0, stream>>>(ei, et, deg8, E);
    k_bsum<<<nb, 256, 0, stream>>>(deg8, bsum, K8);
    k_bscan<<<1, 256, 0, stream>>>(bsum, nb);
    k_bapply<<<nb, 256, 0, stream>>>(deg8, bsum, off8, cursor, K8);
    k_scatd<<<(E + 255)/256, 256, 0, stream>>>(ei, ea, et, cursor, srec, E);
    k_wpack<<<128, 64, 0, stream>>>(W1, W2, wpk);

    int gblocks = (N + 63)/64;
    int aggBlocks = 4096;
    // ---- layer 1 ----
    int Gc1 = (G < 8) ? G : 8;
    k_vgemmB<<<gblocks, 256, 0, stream>>>(nbuf, wpk, 0, 0, Gc1, Vbf, planeElems, N);
    k_agg1e<<<aggBlocks, 256, 0, stream>>>(srec, off8, Vbf, planeElems, W1, We, be,
                                           acc1, N, Gc1);
    for (int g0 = Gc1; g0 < 8; g0 += G) {
        int Gc = (8 - g0 < G) ? (8 - g0) : G;
        k_vgemmB<<<gblocks, 256, 0, stream>>>(nbuf, wpk, 0, g0, Gc, Vbf, planeElems, N);
        k_agg1v<<<aggBlocks, 256, 0, stream>>>(srec, off8, Vbf, planeElems,
                                               acc1, N, g0, g0 + Gc);
    }
    k_hrow<<<N, 64, 0, stream>>>(acc1, acc2, Wroot2, b2);
    // ---- layer 2 ----
    for (int g0 = 0; g0 < 8; g0 += G) {
        int Gc = (8 - g0 < G) ? (8 - g0) : G;
        k_vgemmB<<<gblocks, 256, 0, stream>>>(acc1, wpk, 16, g0, Gc, Vbf, planeElems, N);
        k_agg2<<<aggBlocks, 256, 0, stream>>>(srec, off8, Vbf, planeElems,
                                              acc2, N, g0, g0 + Gc);
    }
    k_final<<<N, 64, 0, stream>>>(acc2, omega, Wo, bo, Wagg, bagg, Wc, bc, out);
}